// Round 9
// baseline (57236.853 us; speedup 1.0000x reference)
//
#include <hip/hip_runtime.h>
#include <hip/hip_bf16.h>

#define NB 64
#define NS 512
#define NI 64
#define NE 256
#define ND 256
#define N4E 1024
#define N4D 1024
#define NTE 512   // 2*E

__device__ __forceinline__ float fsig(float x){
    return __fdividef(1.f, 1.f + __expf(-x));
}
__device__ __forceinline__ float ftanh(float x){
    return 1.f - __fdividef(2.f, 1.f + __expf(2.f*x));
}
__device__ __forceinline__ float wave_sum(float v){
    #pragma unroll
    for (int o=32;o>0;o>>=1) v += __shfl_xor(v, o, 64);
    return v;
}
__device__ __forceinline__ float wave_max(float v){
    #pragma unroll
    for (int o=32;o>0;o>>=1) v = fmaxf(v, __shfl_xor(v, o, 64));
    return v;
}
__device__ __forceinline__ float blo(unsigned u){ return __uint_as_float(u<<16); }
__device__ __forceinline__ float bhi(unsigned u){ return __uint_as_float(u & 0xffff0000u); }
__device__ __forceinline__ unsigned short bfbits(float f){
    __hip_bfloat16 h = __float2bfloat16(f);
    return *(unsigned short*)&h;
}

// fp32 transpose: dst[c*R + r] = src[r*ld + off + c]
__global__ void k_transpose(float* __restrict__ dst, const float* __restrict__ src,
                            int R, int C, int ld, int off){
    int idx = blockIdx.x*256 + threadIdx.x;
    if (idx >= R*C) return;
    int r = idx / C, c = idx - r*C;
    dst[(size_t)c*R + r] = src[(size_t)r*ld + off + c];
}
// bf16 transpose
__global__ void k_transpose16(__hip_bfloat16* __restrict__ dst, const float* __restrict__ src,
                              int R, int C, int ld, int off){
    int idx = blockIdx.x*256 + threadIdx.x;
    if (idx >= R*C) return;
    int r = idx / C, c = idx - r*C;
    dst[(size_t)c*R + r] = __float2bfloat16(src[(size_t)r*ld + off + c]);
}

__global__ void k_pack_wy(float* __restrict__ wy, const float* __restrict__ Wih_d){
    int j = blockIdx.x*256 + threadIdx.x;
    if (j < N4D) wy[j] = Wih_d[(size_t)j*(NTE+1)];
}

// zc[b][j] = b_d[j] + sum_d h0d[b][d] * Whh_d[j][d]  (WhhTd is [d][j] fp32)
__global__ void k_zc(float* __restrict__ zc, const float* __restrict__ WhhTd,
                     const float* __restrict__ h0d, const float* __restrict__ b_d){
    int b = blockIdx.x, tid = threadIdx.x;
    __shared__ float h0[ND];
    if (tid < ND) h0[tid] = h0d[b*ND + tid];
    __syncthreads();
    for (int j = tid; j < N4D; j += 256){
        float acc = b_d[j];
        #pragma unroll 8
        for (int d=0; d<ND; ++d) acc = fmaf(h0[d], WhhTd[d*N4D + j], acc);
        zc[b*N4D + j] = acc;
    }
}

// Encoder (r5 structure, proven): 128 blocks = (dir,b), 1024 threads (j2, kh).
__global__ __launch_bounds__(1024) void k_enc(
    const float* __restrict__ x, const float* __restrict__ eh0, const float* __restrict__ ec0,
    const unsigned* __restrict__ whhTf, const unsigned* __restrict__ wihTf, const float* __restrict__ bf,
    const unsigned* __restrict__ whhTb, const unsigned* __restrict__ wihTb, const float* __restrict__ bb,
    unsigned* __restrict__ eo32)
{
    int bid = blockIdx.x;
    int b = bid & 63, dir = bid >> 6;
    int tid = threadIdx.x;
    int j2 = tid & 511, kh = tid >> 9;
    const unsigned* whh = dir ? whhTb : whhTf;   // [d][512 u32]
    const unsigned* wih = dir ? wihTb : wihTf;   // [i][512 u32]
    const float* bias = dir ? bb : bf;

    __shared__ __align__(16) float h_l[NE];
    __shared__ __align__(16) float xt[2][NI];
    __shared__ float zp0[N4E], zp1[N4E];

    float2 bias2 = make_float2(0.f, 0.f);
    if (kh == 0) bias2 = ((const float2*)bias)[j2];

    float cst = 0.f;
    if (tid < NE){
        h_l[tid] = eh0[(dir*NB+b)*NE + tid];
        cst      = ec0[(dir*NB+b)*NE + tid];
    }
    {
        int st0 = dir ? (NS-1) : 0;
        if (tid < 16) ((float4*)xt[0])[tid] = ((const float4*)(x + ((size_t)b*NS+st0)*NI))[tid];
    }
    __syncthreads();

    const unsigned* wihK = wih + (size_t)(kh*32)*512 + j2;
    const unsigned* whhK = whh + (size_t)(kh*128)*512 + j2;
    float* zpme = kh ? zp1 : zp0;

    for (int t=0;t<NS;++t){
        int st = dir ? (NS-1-t) : t;
        float4 xpre = make_float4(0.f,0.f,0.f,0.f);
        if (t+1 < NS && tid < 16){
            int stn = dir ? (NS-2-t) : (t+1);
            xpre = ((const float4*)(x + ((size_t)b*NS+stn)*NI))[tid];
        }
        const float* xc = xt[t&1];
        float x0=bias2.x, y0=bias2.y, x1=0.f, y1=0.f;
        #pragma unroll 8
        for (int ii=0; ii<32; ii+=2){
            int i = kh*32 + ii;
            unsigned wa = wihK[(size_t)ii*512];
            unsigned wb = wihK[(size_t)(ii+1)*512];
            float xa = xc[i], xb = xc[i+1];
            x0 = fmaf(xa, blo(wa), x0); y0 = fmaf(xa, bhi(wa), y0);
            x1 = fmaf(xb, blo(wb), x1); y1 = fmaf(xb, bhi(wb), y1);
        }
        #pragma unroll 8
        for (int dd=0; dd<128; dd+=2){
            int d = kh*128 + dd;
            unsigned wa = whhK[(size_t)dd*512];
            unsigned wb = whhK[(size_t)(dd+1)*512];
            float ha = h_l[d], hb = h_l[d+1];
            x0 = fmaf(ha, blo(wa), x0); y0 = fmaf(ha, bhi(wa), y0);
            x1 = fmaf(hb, blo(wb), x1); y1 = fmaf(hb, bhi(wb), y1);
        }
        ((float2*)zpme)[j2] = make_float2(x0+x1, y0+y1);
        if (t+1 < NS && tid < 16) ((float4*)xt[(t+1)&1])[tid] = xpre;
        __syncthreads();
        if (tid < NE){
            int c = tid;
            float zi = zp0[c]        + zp1[c];
            float zf = zp0[NE+c]     + zp1[NE+c];
            float zg = zp0[2*NE+c]   + zp1[2*NE+c];
            float zo = zp0[3*NE+c]   + zp1[3*NE+c];
            cst = fsig(zf)*cst + fsig(zi)*ftanh(zg);
            float hn = fsig(zo)*ftanh(cst);
            h_l[c] = hn;
            ((unsigned short*)eo32)[((size_t)b*NS+st)*NTE + dir*NE + c] = bfbits(hn);
        }
        __syncthreads();
    }
}

// ep_pk[b][dp 128][s 512] u32 (bf16 pair d=2dp,2dp+1)
__global__ __launch_bounds__(256) void k_encproj(const unsigned* __restrict__ eo32,
        const float* __restrict__ WeT, const float* __restrict__ b_attn,
        unsigned short* __restrict__ ep_pk16){
    int b = blockIdx.y, s0 = blockIdx.x*16, tid = threadIdx.x;
    __shared__ float tile[16*NTE];
    {
        const unsigned* eop = eo32 + (size_t)(b*NS + s0)*256;
        for (int k=0;k<32;++k){
            int wi = k*256 + tid;
            unsigned w = eop[wi];
            int sl = wi>>8, ew = wi&255;
            tile[sl*NTE + 2*ew]   = blo(w);
            tile[sl*NTE + 2*ew+1] = bhi(w);
        }
    }
    __syncthreads();
    float acc[16];
    float ba = b_attn[tid];
    #pragma unroll
    for (int sl=0;sl<16;++sl) acc[sl]=ba;
    #pragma unroll 4
    for (int e4=0;e4<128;++e4){
        float w0 = WeT[(4*e4+0)*ND+tid];
        float w1 = WeT[(4*e4+1)*ND+tid];
        float w2 = WeT[(4*e4+2)*ND+tid];
        float w3 = WeT[(4*e4+3)*ND+tid];
        #pragma unroll
        for (int sl=0;sl<16;++sl){
            const float4 tv = *(const float4*)&tile[sl*NTE + 4*e4];
            acc[sl] = fmaf(tv.x,w0,fmaf(tv.y,w1,fmaf(tv.z,w2,fmaf(tv.w,w3,acc[sl]))));
        }
    }
    #pragma unroll
    for (int sl=0;sl<16;++sl){
        int s = s0+sl;
        size_t wdi = ((size_t)(b*128) + (tid>>1))*NS + s;
        ep_pk16[wdi*2 + (tid&1)] = bfbits(acc[sl]);
    }
}

// Decoder: 64 blocks (one batch each), 1024 threads, 512 internal steps,
// ZERO cross-block sync. All operands streamed as coalesced uint4 from L2/LLC.
__global__ __launch_bounds__(1024, 1) void k_dec(
    const uint4* __restrict__ eo4,    // [b*512 s][64]  bf16 e-pairs
    const uint4* __restrict__ ep4,    // [b][128 dp][128 s4]
    const uint4* __restrict__ whT4,   // [256 k][32]    bf16 d-pairs
    const uint4* __restrict__ wdT4,   // [512 e][128]   bf16 j-pairs
    const float* __restrict__ v,
    const float* __restrict__ zc, const float* __restrict__ wy,
    const float* __restrict__ dec_h0, const float* __restrict__ dec_c0,
    const float* __restrict__ W_lin, const float* __restrict__ b_lin,
    float* __restrict__ out)
{
    int b = blockIdx.x, tid = threadIdx.x;

    __shared__ float part[8192];      // 32 KB shared scratch for all merges
    __shared__ float2 hv[ND];         // (v[d], hproj[d])
    __shared__ float h_l[ND];
    __shared__ float scores_l[NS];
    __shared__ float ctx_l[NTE];
    __shared__ float z_l[N4D], zc_l[N4D], wy_l[N4D];
    __shared__ float c0_l[ND], wlh_l[ND], wlc_l[NTE];
    __shared__ float wred[16];
    __shared__ float yprevS;

    zc_l[tid] = zc[b*N4D + tid];
    wy_l[tid] = wy[tid];
    if (tid < ND){
        hv[tid]    = make_float2(v[tid], 0.f);
        h_l[tid]   = dec_h0[b*ND + tid];
        c0_l[tid]  = dec_c0[b*ND + tid];
        wlh_l[tid] = W_lin[tid];
    }
    if (tid < NTE) wlc_l[tid] = W_lin[ND + tid];
    if (tid == 0) yprevS = 0.f;
    float blin = b_lin[0];
    __syncthreads();

    const uint4* epb = ep4 + (size_t)b*128*128;
    const uint4* eob = eo4 + (size_t)b*NS*64;

    for (int t=0; t<NS; ++t){
        // ---- 1: hproj = h @ WhT  (stream 128 KB) ----
        {
            int d4 = tid & 31, kq = tid >> 5;     // 32 groups x 8 k
            float ax[8];
            #pragma unroll
            for (int j=0;j<8;++j) ax[j]=0.f;
            #pragma unroll
            for (int kk=0; kk<8; ++kk){
                int k = kq*8 + kk;
                uint4 w = whT4[k*32 + d4];
                float hvv = h_l[k];
                ax[0]=fmaf(hvv,blo(w.x),ax[0]); ax[1]=fmaf(hvv,bhi(w.x),ax[1]);
                ax[2]=fmaf(hvv,blo(w.y),ax[2]); ax[3]=fmaf(hvv,bhi(w.y),ax[3]);
                ax[4]=fmaf(hvv,blo(w.z),ax[4]); ax[5]=fmaf(hvv,bhi(w.z),ax[5]);
                ax[6]=fmaf(hvv,blo(w.w),ax[6]); ax[7]=fmaf(hvv,bhi(w.w),ax[7]);
            }
            #pragma unroll
            for (int j=0;j<8;++j) part[kq*256 + d4*8 + j] = ax[j];
        }
        __syncthreads();
        if (tid < ND){
            float s = 0.f;
            #pragma unroll
            for (int g=0; g<32; ++g) s += part[g*256 + tid];
            hv[tid].y = s;
        }
        __syncthreads();
        // ---- 2: scores[s] = sum_d v[d] tanh(ep + hproj)  (stream 256 KB) ----
        {
            int s4 = tid & 127, dh = tid >> 7;    // 8 groups x 16 dp
            float sc[4];
            #pragma unroll
            for (int j=0;j<4;++j) sc[j]=0.f;
            #pragma unroll
            for (int k=0; k<16; ++k){
                int dp = dh*16 + k;
                uint4 w = epb[dp*128 + s4];
                float2 a0 = hv[2*dp], a1 = hv[2*dp+1];
                const unsigned* ws = &w.x;
                #pragma unroll
                for (int su=0; su<4; ++su){
                    unsigned ww = ws[su];
                    sc[su] += a0.x*ftanh(blo(ww)+a0.y) + a1.x*ftanh(bhi(ww)+a1.y);
                }
            }
            #pragma unroll
            for (int su=0; su<4; ++su) part[dh*512 + s4*4 + su] = sc[su];
        }
        __syncthreads();
        {
            float scval = -1e30f;
            if (tid < NS){
                scval = 0.f;
                #pragma unroll
                for (int g=0; g<8; ++g) scval += part[g*512 + tid];
            }
            float wm = wave_max(scval);
            if ((tid&63)==0 && tid < NS) wred[tid>>6] = wm;
            __syncthreads();
            if (tid < NS){
                float mm = wred[0];
                #pragma unroll
                for (int g=1; g<8; ++g) mm = fmaxf(mm, wred[g]);
                float ev = __expf(scval - mm);
                scores_l[tid] = ev;
                float sw = wave_sum(ev);
                if ((tid&63)==0) wred[8+(tid>>6)] = sw;
            }
        }
        __syncthreads();
        // ---- 3: context[e] = sum_s p[s] eo[s][e]  (stream 512 KB) ----
        {
            int e4 = tid & 63, sq = tid >> 6;     // 16 groups x 32 s
            float ax[8];
            #pragma unroll
            for (int j=0;j<8;++j) ax[j]=0.f;
            #pragma unroll 8
            for (int ss=0; ss<32; ++ss){
                int s = sq*32 + ss;
                uint4 w = eob[s*64 + e4];
                float p = scores_l[s];
                ax[0]=fmaf(p,blo(w.x),ax[0]); ax[1]=fmaf(p,bhi(w.x),ax[1]);
                ax[2]=fmaf(p,blo(w.y),ax[2]); ax[3]=fmaf(p,bhi(w.y),ax[3]);
                ax[4]=fmaf(p,blo(w.z),ax[4]); ax[5]=fmaf(p,bhi(w.z),ax[5]);
                ax[6]=fmaf(p,blo(w.w),ax[6]); ax[7]=fmaf(p,bhi(w.w),ax[7]);
            }
            #pragma unroll
            for (int j=0;j<8;++j) part[sq*512 + e4*8 + j] = ax[j];
        }
        __syncthreads();
        if (tid < NTE){
            float den = wred[8];
            #pragma unroll
            for (int g=9; g<16; ++g) den += wred[g];
            float inv = __fdividef(1.f, den);
            float s = 0.f;
            #pragma unroll
            for (int g=0; g<16; ++g) s += part[g*512 + tid];
            ctx_l[tid] = s * inv;
        }
        __syncthreads();
        // ---- 4: z[j] = zc + y*wy + ctx @ WdT  (stream 1 MB) ----
        {
            int j4 = tid & 127, eq = tid >> 7;    // 8 groups x 64 e
            float ax[8];
            #pragma unroll
            for (int j=0;j<8;++j) ax[j]=0.f;
            #pragma unroll 16
            for (int ee=0; ee<64; ++ee){
                int e = eq*64 + ee;
                uint4 w = wdT4[e*128 + j4];
                float cv = ctx_l[e];
                ax[0]=fmaf(cv,blo(w.x),ax[0]); ax[1]=fmaf(cv,bhi(w.x),ax[1]);
                ax[2]=fmaf(cv,blo(w.y),ax[2]); ax[3]=fmaf(cv,bhi(w.y),ax[3]);
                ax[4]=fmaf(cv,blo(w.z),ax[4]); ax[5]=fmaf(cv,bhi(w.z),ax[5]);
                ax[6]=fmaf(cv,blo(w.w),ax[6]); ax[7]=fmaf(cv,bhi(w.w),ax[7]);
            }
            #pragma unroll
            for (int j=0;j<8;++j) part[eq*1024 + j4*8 + j] = ax[j];
        }
        __syncthreads();
        {
            float s = zc_l[tid] + yprevS*wy_l[tid];
            #pragma unroll
            for (int g=0; g<8; ++g) s += part[g*1024 + tid];
            z_l[tid] = s;
        }
        __syncthreads();
        // ---- 5: gates (256 cells) + y ----
        float yp = 0.f;
        if (tid < ND){
            float zi=z_l[tid], zf=z_l[ND+tid], zg=z_l[2*ND+tid], zo=z_l[3*ND+tid];
            float cn = fsig(zf)*c0_l[tid] + fsig(zi)*ftanh(zg);
            float hn = fsig(zo)*ftanh(cn);
            h_l[tid] = hn;
            yp = hn * wlh_l[tid];
        } else if (tid < ND + NTE){
            yp = ctx_l[tid - ND] * wlc_l[tid - ND];
        }
        {
            float s = wave_sum(yp);
            if ((tid&63)==0 && tid < 768) wred[tid>>6] = s;
        }
        __syncthreads();
        if (tid == 0){
            float y = blin;
            #pragma unroll
            for (int g=0; g<12; ++g) y += wred[g];
            out[(size_t)b*NS + t] = y;
            yprevS = y;
        }
        __syncthreads();
    }
}

extern "C" void kernel_launch(void* const* d_in, const int* in_sizes, int n_in,
                              void* d_out, int out_size, void* d_ws, size_t ws_size,
                              hipStream_t stream){
    const float* x      = (const float*)d_in[0];
    const float* enc_h0 = (const float*)d_in[1];
    const float* enc_c0 = (const float*)d_in[2];
    const float* dec_h0 = (const float*)d_in[3];
    const float* dec_c0 = (const float*)d_in[4];
    const float* Wih_f  = (const float*)d_in[5];
    const float* Whh_f  = (const float*)d_in[6];
    const float* b_f    = (const float*)d_in[7];
    const float* Wih_b  = (const float*)d_in[8];
    const float* Whh_b  = (const float*)d_in[9];
    const float* b_b    = (const float*)d_in[10];
    const float* W_attn = (const float*)d_in[11];
    const float* b_attn = (const float*)d_in[12];
    const float* v      = (const float*)d_in[13];
    const float* Wih_d  = (const float*)d_in[14];
    const float* Whh_d  = (const float*)d_in[15];
    const float* b_d    = (const float*)d_in[16];
    const float* W_lin  = (const float*)d_in[17];
    const float* b_lin  = (const float*)d_in[18];
    float* out = (float*)d_out;
    char* ws   = (char*)d_ws;

    size_t off = 0;
    auto alloc = [&](size_t bytes)->size_t{ size_t o = off; off += (bytes + 255) & ~(size_t)255; return o; };
    size_t o_eo16   = alloc((size_t)NB*NS*NTE*2);        // bf16 enc_out
    size_t o_eppk   = alloc((size_t)NB*128*NS*4);        // packed bf16 ep [b][dp][s]
    size_t o_WihTf  = alloc((size_t)NI*N4E*2);           // [i][1024 j] bf16
    size_t o_WhhTf  = alloc((size_t)NE*N4E*2);           // [d][1024 j] bf16
    size_t o_WihTb  = alloc((size_t)NI*N4E*2);
    size_t o_WhhTb  = alloc((size_t)NE*N4E*2);
    size_t o_WhT16  = alloc((size_t)ND*ND*2);            // [k][d] bf16
    size_t o_WeT    = alloc((size_t)NTE*ND*4);
    size_t o_WdT16  = alloc((size_t)NTE*N4D*2);          // [e][j] bf16
    size_t o_WhhTd  = alloc((size_t)ND*N4D*4);
    size_t o_zc     = alloc((size_t)NB*N4D*4);
    size_t o_wy     = alloc((size_t)N4D*4);
    if (ws_size < off) return;

    auto F   = [&](size_t o)->float*{ return (float*)(ws + o); };
    auto U32 = [&](size_t o)->unsigned*{ return (unsigned*)(ws + o); };
    auto U4  = [&](size_t o)->uint4*{ return (uint4*)(ws + o); };
    auto H16 = [&](size_t o)->__hip_bfloat16*{ return (__hip_bfloat16*)(ws + o); };

    auto T32 = [&](size_t dsto, const float* src, int R, int C, int ld, int offc){
        int n = R*C;
        k_transpose<<<dim3((n+255)/256), dim3(256), 0, stream>>>(F(dsto), src, R, C, ld, offc);
    };
    auto T16 = [&](size_t dsto, const float* src, int R, int C, int ld, int offc){
        int n = R*C;
        k_transpose16<<<dim3((n+255)/256), dim3(256), 0, stream>>>(H16(dsto), src, R, C, ld, offc);
    };
    T16(o_WihTf, Wih_f, N4E, NI, NI, 0);
    T16(o_WhhTf, Whh_f, N4E, NE, NE, 0);
    T16(o_WihTb, Wih_b, N4E, NI, NI, 0);
    T16(o_WhhTb, Whh_b, N4E, NE, NE, 0);
    T16(o_WhT16, W_attn, ND, ND, ND+NTE, 0);   // [k][d]
    T32(o_WeT,   W_attn, ND, NTE, ND+NTE, ND);
    T16(o_WdT16, Wih_d, N4D, NTE, NTE+1, 1);   // [e][j]
    T32(o_WhhTd, Whh_d, N4D, ND, ND, 0);
    k_pack_wy<<<dim3(4), dim3(256), 0, stream>>>(F(o_wy), Wih_d);
    k_zc<<<dim3(NB), dim3(256), 0, stream>>>(F(o_zc), F(o_WhhTd), dec_h0, b_d);

    k_enc<<<dim3(2*NB), dim3(1024), 0, stream>>>(x, enc_h0, enc_c0,
        U32(o_WhhTf), U32(o_WihTf), b_f, U32(o_WhhTb), U32(o_WihTb), b_b, U32(o_eo16));

    k_encproj<<<dim3(NS/16, NB), dim3(256), 0, stream>>>(U32(o_eo16), F(o_WeT), b_attn,
        (unsigned short*)(ws+o_eppk));

    k_dec<<<dim3(NB), dim3(1024), 0, stream>>>(U4(o_eo16), U4(o_eppk),
        U4(o_WhT16), U4(o_WdT16), v, F(o_zc), F(o_wy), dec_h0, dec_c0, W_lin, b_lin, out);
}

// Round 10
// 25727.985 us; speedup vs baseline: 2.2247x; 2.2247x over previous
//
#include <hip/hip_runtime.h>
#include <hip/hip_bf16.h>

#define NB 64
#define NS 512
#define NI 64
#define NE 256
#define ND 256
#define N4E 1024
#define N4D 1024
#define NTE 512   // 2*E
#define G 4
#define SLICE 128 // NS/G
#define CELLS 64  // ND/G

__device__ __forceinline__ float fsig(float x){
    return __fdividef(1.f, 1.f + __expf(-x));
}
__device__ __forceinline__ float ftanh(float x){
    return 1.f - __fdividef(2.f, 1.f + __expf(2.f*x));
}
__device__ __forceinline__ float wave_sum(float v){
    #pragma unroll
    for (int o=32;o>0;o>>=1) v += __shfl_xor(v, o, 64);
    return v;
}
__device__ __forceinline__ float wave_max(float v){
    #pragma unroll
    for (int o=32;o>0;o>>=1) v = fmaxf(v, __shfl_xor(v, o, 64));
    return v;
}
__device__ __forceinline__ float blo(unsigned u){ return __uint_as_float(u<<16); }
__device__ __forceinline__ float bhi(unsigned u){ return __uint_as_float(u & 0xffff0000u); }
__device__ __forceinline__ unsigned short bfbits(float f){
    __hip_bfloat16 h = __float2bfloat16(f);
    return *(unsigned short*)&h;
}
__device__ __forceinline__ float ld_agf(const float* p){
    return __hip_atomic_load(p, __ATOMIC_RELAXED, __HIP_MEMORY_SCOPE_AGENT);
}
__device__ __forceinline__ void st_agf(float* p, float v){
    __hip_atomic_store(p, v, __ATOMIC_RELAXED, __HIP_MEMORY_SCOPE_AGENT);
}
__device__ __forceinline__ unsigned long long ld_ag64(const unsigned long long* p){
    return __hip_atomic_load(p, __ATOMIC_RELAXED, __HIP_MEMORY_SCOPE_AGENT);
}
__device__ __forceinline__ void st_ag64(unsigned long long* p, unsigned long long v){
    __hip_atomic_store(p, v, __ATOMIC_RELAXED, __HIP_MEMORY_SCOPE_AGENT);
}

// group barrier: per-q flag words (padded 128B per batch); no RMW contention.
__device__ __forceinline__ void groupbar(unsigned* flags, int b, int q,
                                         unsigned tgt, int tid){
    __syncthreads();
    if (tid == 0)
        __hip_atomic_store(&flags[(b<<5)+q], tgt, __ATOMIC_RELAXED, __HIP_MEMORY_SCOPE_AGENT);
    if (tid < G){
        while (__hip_atomic_load(&flags[(b<<5)+tid], __ATOMIC_RELAXED,
                                 __HIP_MEMORY_SCOPE_AGENT) < tgt)
            __builtin_amdgcn_s_sleep(1);
    }
    __syncthreads();
}

// fp32 transpose: dst[c*R + r] = src[r*ld + off + c]
__global__ void k_transpose(float* __restrict__ dst, const float* __restrict__ src,
                            int R, int C, int ld, int off){
    int idx = blockIdx.x*256 + threadIdx.x;
    if (idx >= R*C) return;
    int r = idx / C, c = idx - r*C;
    dst[(size_t)c*R + r] = src[(size_t)r*ld + off + c];
}
// bf16 transpose
__global__ void k_transpose16(__hip_bfloat16* __restrict__ dst, const float* __restrict__ src,
                              int R, int C, int ld, int off){
    int idx = blockIdx.x*256 + threadIdx.x;
    if (idx >= R*C) return;
    int r = idx / C, c = idx - r*C;
    dst[(size_t)c*R + r] = __float2bfloat16(src[(size_t)r*ld + off + c]);
}

__global__ void k_pack_wy(float* __restrict__ wy, const float* __restrict__ Wih_d){
    int j = blockIdx.x*256 + threadIdx.x;
    if (j < N4D) wy[j] = Wih_d[(size_t)j*(NTE+1)];
}

// WdTg16[q][e][jj] = bf16(Wih_d[ (jj>>6)*256 + q*64 + (jj&63) ][ 1 + e ])
__global__ void k_pack_wdtg(__hip_bfloat16* __restrict__ dst, const float* __restrict__ Wih_d){
    int idx = blockIdx.x*256 + threadIdx.x;   // total 4*512*256 = 524288
    int q = idx >> 17, rem = idx & 131071;
    int e = rem >> 8, jj = rem & 255;
    int j = ((jj>>6)<<8) + (q<<6) + (jj&63);
    dst[idx] = __float2bfloat16(Wih_d[(size_t)j*(NTE+1) + 1 + e]);
}

// zc[b][j] = b_d[j] + sum_d h0d[b][d] * Whh_d[j][d]
__global__ void k_zc(float* __restrict__ zc, const float* __restrict__ WhhTd,
                     const float* __restrict__ h0d, const float* __restrict__ b_d){
    int b = blockIdx.x, tid = threadIdx.x;
    __shared__ float h0[ND];
    if (tid < ND) h0[tid] = h0d[b*ND + tid];
    __syncthreads();
    for (int j = tid; j < N4D; j += 256){
        float acc = b_d[j];
        #pragma unroll 8
        for (int d=0; d<ND; ++d) acc = fmaf(h0[d], WhhTd[d*N4D + j], acc);
        zc[b*N4D + j] = acc;
    }
}

__global__ void k_dec_init(float* __restrict__ hG, float* __restrict__ yG,
                           unsigned* __restrict__ flags, const float* __restrict__ dec_h0){
    int b = blockIdx.x, tid = threadIdx.x;
    hG[b*ND + tid] = dec_h0[b*ND + tid];
    if (tid < G){ yG[(b<<5) + tid] = 0.f; flags[(b<<5) + tid] = 0u; }
}

// Encoder (r5 structure, proven): 128 blocks = (dir,b), 1024 threads (j2, kh).
__global__ __launch_bounds__(1024) void k_enc(
    const float* __restrict__ x, const float* __restrict__ eh0, const float* __restrict__ ec0,
    const unsigned* __restrict__ whhTf, const unsigned* __restrict__ wihTf, const float* __restrict__ bf,
    const unsigned* __restrict__ whhTb, const unsigned* __restrict__ wihTb, const float* __restrict__ bb,
    unsigned* __restrict__ eo32)
{
    int bid = blockIdx.x;
    int b = bid & 63, dir = bid >> 6;
    int tid = threadIdx.x;
    int j2 = tid & 511, kh = tid >> 9;
    const unsigned* whh = dir ? whhTb : whhTf;   // [d][512 u32]
    const unsigned* wih = dir ? wihTb : wihTf;   // [i][512 u32]
    const float* bias = dir ? bb : bf;

    __shared__ __align__(16) float h_l[NE];
    __shared__ __align__(16) float xt[2][NI];
    __shared__ float zp0[N4E], zp1[N4E];

    float2 bias2 = make_float2(0.f, 0.f);
    if (kh == 0) bias2 = ((const float2*)bias)[j2];

    float cst = 0.f;
    if (tid < NE){
        h_l[tid] = eh0[(dir*NB+b)*NE + tid];
        cst      = ec0[(dir*NB+b)*NE + tid];
    }
    {
        int st0 = dir ? (NS-1) : 0;
        if (tid < 16) ((float4*)xt[0])[tid] = ((const float4*)(x + ((size_t)b*NS+st0)*NI))[tid];
    }
    __syncthreads();

    const unsigned* wihK = wih + (size_t)(kh*32)*512 + j2;
    const unsigned* whhK = whh + (size_t)(kh*128)*512 + j2;
    float* zpme = kh ? zp1 : zp0;

    for (int t=0;t<NS;++t){
        int st = dir ? (NS-1-t) : t;
        float4 xpre = make_float4(0.f,0.f,0.f,0.f);
        if (t+1 < NS && tid < 16){
            int stn = dir ? (NS-2-t) : (t+1);
            xpre = ((const float4*)(x + ((size_t)b*NS+stn)*NI))[tid];
        }
        const float* xc = xt[t&1];
        float x0=bias2.x, y0=bias2.y, x1=0.f, y1=0.f;
        #pragma unroll 8
        for (int ii=0; ii<32; ii+=2){
            int i = kh*32 + ii;
            unsigned wa = wihK[(size_t)ii*512];
            unsigned wb = wihK[(size_t)(ii+1)*512];
            float xa = xc[i], xb = xc[i+1];
            x0 = fmaf(xa, blo(wa), x0); y0 = fmaf(xa, bhi(wa), y0);
            x1 = fmaf(xb, blo(wb), x1); y1 = fmaf(xb, bhi(wb), y1);
        }
        #pragma unroll 8
        for (int dd=0; dd<128; dd+=2){
            int d = kh*128 + dd;
            unsigned wa = whhK[(size_t)dd*512];
            unsigned wb = whhK[(size_t)(dd+1)*512];
            float ha = h_l[d], hb = h_l[d+1];
            x0 = fmaf(ha, blo(wa), x0); y0 = fmaf(ha, bhi(wa), y0);
            x1 = fmaf(hb, blo(wb), x1); y1 = fmaf(hb, bhi(wb), y1);
        }
        ((float2*)zpme)[j2] = make_float2(x0+x1, y0+y1);
        if (t+1 < NS && tid < 16) ((float4*)xt[(t+1)&1])[tid] = xpre;
        __syncthreads();
        if (tid < NE){
            int c = tid;
            float zi = zp0[c]        + zp1[c];
            float zf = zp0[NE+c]     + zp1[NE+c];
            float zg = zp0[2*NE+c]   + zp1[2*NE+c];
            float zo = zp0[3*NE+c]   + zp1[3*NE+c];
            cst = fsig(zf)*cst + fsig(zi)*ftanh(zg);
            float hn = fsig(zo)*ftanh(cst);
            h_l[c] = hn;
            ((unsigned short*)eo32)[((size_t)b*NS+st)*NTE + dir*NE + c] = bfbits(hn);
        }
        __syncthreads();
    }
}

// ep_pk[b][q(4)][dp 128][s 128] (u32 = bf16 pair d=2dp,2dp+1)
__global__ __launch_bounds__(256) void k_encproj(const unsigned* __restrict__ eo32,
        const float* __restrict__ WeT, const float* __restrict__ b_attn,
        unsigned short* __restrict__ ep_pk16){
    int b = blockIdx.y, s0 = blockIdx.x*16, tid = threadIdx.x;
    __shared__ float tile[16*NTE];
    {
        const unsigned* eop = eo32 + (size_t)(b*NS + s0)*256;
        for (int k=0;k<32;++k){
            int wi = k*256 + tid;
            unsigned w = eop[wi];
            int sl = wi>>8, ew = wi&255;
            tile[sl*NTE + 2*ew]   = blo(w);
            tile[sl*NTE + 2*ew+1] = bhi(w);
        }
    }
    __syncthreads();
    float acc[16];
    float ba = b_attn[tid];
    #pragma unroll
    for (int sl=0;sl<16;++sl) acc[sl]=ba;
    #pragma unroll 4
    for (int e4=0;e4<128;++e4){
        float w0 = WeT[(4*e4+0)*ND+tid];
        float w1 = WeT[(4*e4+1)*ND+tid];
        float w2 = WeT[(4*e4+2)*ND+tid];
        float w3 = WeT[(4*e4+3)*ND+tid];
        #pragma unroll
        for (int sl=0;sl<16;++sl){
            const float4 tv = *(const float4*)&tile[sl*NTE + 4*e4];
            acc[sl] = fmaf(tv.x,w0,fmaf(tv.y,w1,fmaf(tv.z,w2,fmaf(tv.w,w3,acc[sl]))));
        }
    }
    #pragma unroll
    for (int sl=0;sl<16;++sl){
        int s = s0+sl;
        size_t wdi = ((size_t)(b*4 + (s>>7))*128 + (tid>>1))*128 + (s&127);
        ep_pk16[wdi*2 + (tid&1)] = bfbits(acc[sl]);
    }
}

// Cooperative decoder: 256 blocks = 64 batches x 4 slices, 1024 threads.
// r5 structure; WdT quarter held in 64 per-thread REGISTERS (no per-step
// stream); ep quarter in LDS; eo quarter in registers; WhT streamed (L2-hot).
__global__ __launch_bounds__(1024) void k_dec(
    const unsigned* __restrict__ eo32,     // [b*s][256] bf16 e-pairs
    const unsigned* __restrict__ ep_pk,    // [b][q][128 dp][128 s] u32
    const unsigned* __restrict__ WhTp,     // [k 256][128] bf16 d-pairs
    const float* __restrict__ v,
    const float* __restrict__ zc, const float* __restrict__ wy,
    const unsigned* __restrict__ WdTp_all, // [q][512 e][128] bf16 jj-pairs
    const float* __restrict__ dec_c0,
    const float* __restrict__ W_lin, const float* __restrict__ b_lin,
    float* __restrict__ hG, float* __restrict__ yG,
    float* __restrict__ ctxG, float* __restrict__ msG,
    unsigned* __restrict__ flags,
    float* __restrict__ out)
{
    int bid = blockIdx.x;
    int b = bid & 63, q = bid >> 6;
    int tid = threadIdx.x;
    int w = tid >> 6, l = tid & 63;

    __shared__ unsigned ep_lds[16384];   // 64 KB: [128 dp][128 s]
    __shared__ float part[2048];         // 8 KB scratch
    __shared__ float h_l[ND];
    __shared__ float2 hv[ND];            // .x = v[d] (persistent), .y = hproj[d]
    __shared__ float scraw[SLICE];
    __shared__ float scores_p[4*33];     // padded [sq][33]
    __shared__ float ctx_l[NTE];
    __shared__ float z_l[256], zc_l[256], wy_l[256];
    __shared__ float c0_l[CELLS], wlh_l[CELLS], wlc_l[SLICE];
    __shared__ float msbuf[8];
    __shared__ float wred[16];
    __shared__ float yprev;

    const unsigned* WdTp = WdTp_all + (size_t)q*NTE*128;

    for (int i=tid; i<16384; i+=1024)
        ep_lds[i] = ep_pk[(size_t)(b*4+q)*16384 + i];
    // eo slice in registers: thread -> (sq = l&3, ep2 = w*16 + (l>>2))
    unsigned eo_reg[32];
    {
        int sq = l & 3, ep2 = w*16 + (l>>2);
        const unsigned* eop = eo32 + (size_t)(b*NS + q*SLICE + sq*32)*256 + ep2;
        #pragma unroll
        for (int ss=0; ss<32; ++ss) eo_reg[ss] = eop[(size_t)ss*256];
    }
    // WdT quarter in registers: thread (jj2 = tid&127, eq = tid>>7) holds
    // wd_reg[ee] = WdTp[(eq*64+ee)*128 + jj2]
    unsigned wd_reg[64];
    {
        int jj2 = tid & 127, eq = tid >> 7;
        const unsigned* wp = WdTp + (size_t)(eq*64)*128 + jj2;
        #pragma unroll
        for (int ee=0; ee<64; ++ee) wd_reg[ee] = wp[(size_t)ee*128];
    }
    if (tid < 256){
        int jj = tid;
        int j = ((jj>>6)<<8) + (q<<6) + (jj&63);
        zc_l[jj] = zc[b*N4D + j];
        wy_l[jj] = wy[j];
    }
    if (tid < ND) hv[tid] = make_float2(v[tid], 0.f);
    if (tid < CELLS){
        c0_l[tid]  = dec_c0[b*ND + q*CELLS + tid];
        wlh_l[tid] = W_lin[q*CELLS + tid];
    }
    if (tid < SLICE) wlc_l[tid] = W_lin[ND + q*SLICE + tid];
    float blin = b_lin[0];
    __syncthreads();

    for (int t=0; t<NS; ++t){
        // ---- step start: h(t-1), y(t-1) ----
        if (tid < ND) h_l[tid] = ld_agf(&hG[b*ND + tid]);
        if (tid == 0){
            float y = 0.f;
            if (t > 0){
                y = blin + ld_agf(&yG[(b<<5)+0]) + ld_agf(&yG[(b<<5)+1])
                         + ld_agf(&yG[(b<<5)+2]) + ld_agf(&yG[(b<<5)+3]);
                if (q == 0) out[(size_t)b*NS + (t-1)] = y;
            }
            yprev = y;
        }
        __syncthreads();
        // ---- A: hproj = h @ WhT (stream, L2-hot, shared by all blocks) ----
        {
            int d2 = tid & 127, kq = tid >> 7;
            float ax = 0.f, ay = 0.f;
            #pragma unroll 8
            for (int kk=0; kk<32; ++kk){
                int k = kq*32 + kk;
                unsigned ww = WhTp[k*128 + d2];
                float hvv = h_l[k];
                ax = fmaf(hvv, blo(ww), ax); ay = fmaf(hvv, bhi(ww), ay);
            }
            ((float2*)part)[kq*128 + d2] = make_float2(ax, ay);
        }
        __syncthreads();
        if (tid < ND)
            hv[tid].y = part[tid] + part[256+tid] + part[512+tid] + part[768+tid]
                      + part[1024+tid] + part[1280+tid] + part[1536+tid] + part[1792+tid];
        __syncthreads();
        // ---- B: scores from LDS ep (conflict-free) ----
        {
            int sl = tid & 127, dg = tid >> 7;
            float sc = 0.f;
            const unsigned* epl = ep_lds + dg*16*128 + sl;
            #pragma unroll
            for (int k16=0; k16<16; ++k16){
                unsigned ww = epl[k16*128];
                int d = dg*32 + 2*k16;
                float2 a0 = hv[d], a1 = hv[d+1];
                sc += a0.x*ftanh(blo(ww) + a0.y) + a1.x*ftanh(bhi(ww) + a1.y);
            }
            part[dg*128 + sl] = sc;
        }
        __syncthreads();
        if (tid < SLICE){
            float s = 0.f;
            #pragma unroll
            for (int r=0;r<8;++r) s += part[r*128 + tid];
            scraw[tid] = s;
            float wm = wave_max(s);
            if ((tid&63)==0) wred[tid>>6] = wm;
        }
        __syncthreads();
        float smax = fmaxf(wred[0], wred[1]);
        if (tid < SLICE){
            float ev = __expf(scraw[tid] - smax);
            scores_p[(tid>>5)*33 + (tid&31)] = ev;
            float s = wave_sum(ev);
            if ((tid&63)==0) wred[2+(tid>>6)] = s;
        }
        __syncthreads();
        if (tid == 0){
            st_agf(&msG[(b<<5) + 2*q + 0], smax);
            st_agf(&msG[(b<<5) + 2*q + 1], wred[2]+wred[3]);
        }
        // ---- C: context partial; sq folded via shfl ----
        {
            int sq = l & 3, ep2 = w*16 + (l>>2);
            float ax = 0.f, ay = 0.f;
            const float* sp = scores_p + sq*33;
            #pragma unroll
            for (int ss=0; ss<32; ++ss){
                float p = sp[ss];
                unsigned e = eo_reg[ss];
                ax = fmaf(p, blo(e), ax); ay = fmaf(p, bhi(e), ay);
            }
            ax += __shfl_xor(ax, 1, 64); ay += __shfl_xor(ay, 1, 64);
            ax += __shfl_xor(ax, 2, 64); ay += __shfl_xor(ay, 2, 64);
            if (sq == 0) ((float2*)part)[ep2] = make_float2(ax, ay);
        }
        __syncthreads();
        if (tid < 256){
            float2 c2 = ((float2*)part)[tid];
            st_ag64((unsigned long long*)(ctxG + (size_t)(b*4+q)*NTE + 2*tid),
                    *(unsigned long long*)&c2);
        }
        groupbar(flags, b, q, (unsigned)(2*t+1), tid);
        // ---- D: merge softmax+context ----
        unsigned long long cg[4];
        if (tid < 8) msbuf[tid] = ld_agf(&msG[(b<<5) + tid]);
        if (tid < 256){
            const unsigned long long* cgp =
                (const unsigned long long*)(ctxG + (size_t)b*4*NTE) + tid;
            #pragma unroll
            for (int qq=0; qq<4; ++qq) cg[qq] = ld_ag64(cgp + qq*256);
        }
        __syncthreads();
        if (tid < 256){
            float mm = fmaxf(fmaxf(msbuf[0], msbuf[2]), fmaxf(msbuf[4], msbuf[6]));
            float w0 = __expf(msbuf[0]-mm), w1 = __expf(msbuf[2]-mm),
                  w2 = __expf(msbuf[4]-mm), w3 = __expf(msbuf[6]-mm);
            float inv = __fdividef(1.f, msbuf[1]*w0 + msbuf[3]*w1 + msbuf[5]*w2 + msbuf[7]*w3);
            float2 c0v = *(float2*)&cg[0], c1v = *(float2*)&cg[1];
            float2 c2v = *(float2*)&cg[2], c3v = *(float2*)&cg[3];
            float ax = c0v.x*w0 + c1v.x*w1 + c2v.x*w2 + c3v.x*w3;
            float ay = c0v.y*w0 + c1v.y*w1 + c2v.y*w2 + c3v.y*w3;
            ((float2*)ctx_l)[tid] = make_float2(ax*inv, ay*inv);
        }
        __syncthreads();
        // ---- z j-slice from REGISTER-resident WdT (zero memory traffic) ----
        {
            int jj2 = tid & 127, eq = tid >> 7;
            float ax = 0.f, ay = 0.f;
            #pragma unroll
            for (int ee=0; ee<64; ++ee){
                float cv = ctx_l[eq*64 + ee];   // wave-uniform -> LDS broadcast
                unsigned ww = wd_reg[ee];
                ax = fmaf(cv, blo(ww), ax); ay = fmaf(cv, bhi(ww), ay);
            }
            ((float2*)part)[eq*128 + jj2] = make_float2(ax, ay);
        }
        __syncthreads();
        if (tid < 256){
            float s = zc_l[tid] + yprev*wy_l[tid];
            #pragma unroll
            for (int r=0; r<8; ++r) s += part[r*256 + tid];
            z_l[tid] = s;
        }
        __syncthreads();
        // ---- gates (64 cells) + y partials ----
        float yp = 0.f;
        if (tid < CELLS){
            float zi=z_l[tid], zf=z_l[64+tid], zg=z_l[128+tid], zo=z_l[192+tid];
            float cn = fsig(zf)*c0_l[tid] + fsig(zi)*ftanh(zg);
            float hn = fsig(zo)*ftanh(cn);
            st_agf(&hG[b*ND + q*CELLS + tid], hn);
            yp = hn * wlh_l[tid];
        } else if (tid < CELLS + SLICE){
            yp = ctx_l[q*SLICE + (tid - CELLS)] * wlc_l[tid - CELLS];
        }
        {
            float s = wave_sum(yp);
            if ((tid&63)==0 && tid < 192) wred[8+(tid>>6)] = s;
        }
        __syncthreads();
        if (tid == 0) st_agf(&yG[(b<<5) + q], wred[8]+wred[9]+wred[10]);
        groupbar(flags, b, q, (unsigned)(2*t+2), tid);
    }
    if (q == 0 && tid == 0){
        out[(size_t)b*NS + (NS-1)] = blin + ld_agf(&yG[(b<<5)+0]) + ld_agf(&yG[(b<<5)+1])
                                          + ld_agf(&yG[(b<<5)+2]) + ld_agf(&yG[(b<<5)+3]);
    }
}

extern "C" void kernel_launch(void* const* d_in, const int* in_sizes, int n_in,
                              void* d_out, int out_size, void* d_ws, size_t ws_size,
                              hipStream_t stream){
    const float* x      = (const float*)d_in[0];
    const float* enc_h0 = (const float*)d_in[1];
    const float* enc_c0 = (const float*)d_in[2];
    const float* dec_h0 = (const float*)d_in[3];
    const float* dec_c0 = (const float*)d_in[4];
    const float* Wih_f  = (const float*)d_in[5];
    const float* Whh_f  = (const float*)d_in[6];
    const float* b_f    = (const float*)d_in[7];
    const float* Wih_b  = (const float*)d_in[8];
    const float* Whh_b  = (const float*)d_in[9];
    const float* b_b    = (const float*)d_in[10];
    const float* W_attn = (const float*)d_in[11];
    const float* b_attn = (const float*)d_in[12];
    const float* v      = (const float*)d_in[13];
    const float* Wih_d  = (const float*)d_in[14];
    const float* Whh_d  = (const float*)d_in[15];
    const float* b_d    = (const float*)d_in[16];
    const float* W_lin  = (const float*)d_in[17];
    const float* b_lin  = (const float*)d_in[18];
    float* out = (float*)d_out;
    char* ws   = (char*)d_ws;

    size_t off = 0;
    auto alloc = [&](size_t bytes)->size_t{ size_t o = off; off += (bytes + 255) & ~(size_t)255; return o; };
    size_t o_eo16   = alloc((size_t)NB*NS*NTE*2);        // bf16 enc_out
    size_t o_eppk   = alloc((size_t)NB*G*128*128*4);     // packed bf16 ep
    size_t o_WihTf  = alloc((size_t)NI*N4E*2);           // [i][1024 j] bf16
    size_t o_WhhTf  = alloc((size_t)NE*N4E*2);           // [d][1024 j] bf16
    size_t o_WihTb  = alloc((size_t)NI*N4E*2);
    size_t o_WhhTb  = alloc((size_t)NE*N4E*2);
    size_t o_WhT16  = alloc((size_t)ND*ND*2);
    size_t o_WeT    = alloc((size_t)NTE*ND*4);
    size_t o_WdTg   = alloc((size_t)G*NTE*256*2);
    size_t o_WhhTd  = alloc((size_t)ND*N4D*4);
    size_t o_zc     = alloc((size_t)NB*N4D*4);
    size_t o_wy     = alloc((size_t)N4D*4);
    size_t o_hG     = alloc((size_t)NB*ND*4);
    size_t o_yG     = alloc((size_t)NB*32*4);
    size_t o_ctxG   = alloc((size_t)NB*G*NTE*4);
    size_t o_msG    = alloc((size_t)NB*32*4);
    size_t o_flags  = alloc((size_t)NB*32*4);
    if (ws_size < off) return;

    auto F   = [&](size_t o)->float*{ return (float*)(ws + o); };
    auto U32 = [&](size_t o)->unsigned*{ return (unsigned*)(ws + o); };
    auto H16 = [&](size_t o)->__hip_bfloat16*{ return (__hip_bfloat16*)(ws + o); };

    auto T32 = [&](size_t dsto, const float* src, int R, int C, int ld, int offc){
        int n = R*C;
        k_transpose<<<dim3((n+255)/256), dim3(256), 0, stream>>>(F(dsto), src, R, C, ld, offc);
    };
    auto T16 = [&](size_t dsto, const float* src, int R, int C, int ld, int offc){
        int n = R*C;
        k_transpose16<<<dim3((n+255)/256), dim3(256), 0, stream>>>(H16(dsto), src, R, C, ld, offc);
    };
    T16(o_WihTf, Wih_f, N4E, NI, NI, 0);
    T16(o_WhhTf, Whh_f, N4E, NE, NE, 0);
    T16(o_WihTb, Wih_b, N4E, NI, NI, 0);
    T16(o_WhhTb, Whh_b, N4E, NE, NE, 0);
    T16(o_WhT16, W_attn, ND, ND, ND+NTE, 0);
    T32(o_WeT,   W_attn, ND, NTE, ND+NTE, ND);
    T32(o_WhhTd, Whh_d, N4D, ND, ND, 0);
    k_pack_wdtg<<<dim3((G*NTE*256)/256), dim3(256), 0, stream>>>(H16(o_WdTg), Wih_d);
    k_pack_wy<<<dim3(4), dim3(256), 0, stream>>>(F(o_wy), Wih_d);
    k_zc<<<dim3(NB), dim3(256), 0, stream>>>(F(o_zc), F(o_WhhTd), dec_h0, b_d);
    k_dec_init<<<dim3(NB), dim3(256), 0, stream>>>(F(o_hG), F(o_yG), (unsigned*)(ws+o_flags), dec_h0);

    k_enc<<<dim3(2*NB), dim3(1024), 0, stream>>>(x, enc_h0, enc_c0,
        U32(o_WhhTf), U32(o_WihTf), b_f, U32(o_WhhTb), U32(o_WihTb), b_b, U32(o_eo16));

    k_encproj<<<dim3(NS/16, NB), dim3(256), 0, stream>>>(U32(o_eo16), F(o_WeT), b_attn,
        (unsigned short*)(ws+o_eppk));

    k_dec<<<dim3(NB*G), dim3(1024), 0, stream>>>(U32(o_eo16), U32(o_eppk),
        U32(o_WhT16), v, F(o_zc), F(o_wy), U32(o_WdTg), dec_c0, W_lin, b_lin,
        F(o_hG), F(o_yG), F(o_ctxG), F(o_msG), (unsigned*)(ws+o_flags), out);
}

// Round 11
// 18399.484 us; speedup vs baseline: 3.1108x; 1.3983x over previous
//
#include <hip/hip_runtime.h>
#include <hip/hip_bf16.h>

#define NB 64
#define NS 512
#define NI 64
#define NE 256
#define ND 256
#define N4E 1024
#define N4D 1024
#define NTE 512   // 2*E
#define G 4
#define SLICE 128 // NS/G
#define CELLS 64  // ND/G

__device__ __forceinline__ float fsig(float x){
    return __fdividef(1.f, 1.f + __expf(-x));
}
__device__ __forceinline__ float ftanh(float x){
    return 1.f - __fdividef(2.f, 1.f + __expf(2.f*x));
}
__device__ __forceinline__ float wave_sum(float v){
    #pragma unroll
    for (int o=32;o>0;o>>=1) v += __shfl_xor(v, o, 64);
    return v;
}
__device__ __forceinline__ float wave_max(float v){
    #pragma unroll
    for (int o=32;o>0;o>>=1) v = fmaxf(v, __shfl_xor(v, o, 64));
    return v;
}
__device__ __forceinline__ float blo(unsigned u){ return __uint_as_float(u<<16); }
__device__ __forceinline__ float bhi(unsigned u){ return __uint_as_float(u & 0xffff0000u); }
__device__ __forceinline__ unsigned short bfbits(float f){
    __hip_bfloat16 h = __float2bfloat16(f);
    return *(unsigned short*)&h;
}
__device__ __forceinline__ float ld_agf(const float* p){
    return __hip_atomic_load(p, __ATOMIC_RELAXED, __HIP_MEMORY_SCOPE_AGENT);
}
__device__ __forceinline__ void st_agf(float* p, float v){
    __hip_atomic_store(p, v, __ATOMIC_RELAXED, __HIP_MEMORY_SCOPE_AGENT);
}
__device__ __forceinline__ unsigned long long ld_ag64(const unsigned long long* p){
    return __hip_atomic_load(p, __ATOMIC_RELAXED, __HIP_MEMORY_SCOPE_AGENT);
}
__device__ __forceinline__ void st_ag64(unsigned long long* p, unsigned long long v){
    __hip_atomic_store(p, v, __ATOMIC_RELAXED, __HIP_MEMORY_SCOPE_AGENT);
}

// group barrier: per-q flag words (padded 128B per batch); tight 4-lane poll.
__device__ __forceinline__ void groupbar(unsigned* flags, int b, int q,
                                         unsigned tgt, int tid){
    __syncthreads();
    if (tid == 0)
        __hip_atomic_store(&flags[(b<<5)+q], tgt, __ATOMIC_RELAXED, __HIP_MEMORY_SCOPE_AGENT);
    if (tid < G){
        while (__hip_atomic_load(&flags[(b<<5)+tid], __ATOMIC_RELAXED,
                                 __HIP_MEMORY_SCOPE_AGENT) < tgt)
            ;
    }
    __syncthreads();
}

// fp32 transpose: dst[c*R + r] = src[r*ld + off + c]
__global__ void k_transpose(float* __restrict__ dst, const float* __restrict__ src,
                            int R, int C, int ld, int off){
    int idx = blockIdx.x*256 + threadIdx.x;
    if (idx >= R*C) return;
    int r = idx / C, c = idx - r*C;
    dst[(size_t)c*R + r] = src[(size_t)r*ld + off + c];
}
// bf16 transpose
__global__ void k_transpose16(__hip_bfloat16* __restrict__ dst, const float* __restrict__ src,
                              int R, int C, int ld, int off){
    int idx = blockIdx.x*256 + threadIdx.x;
    if (idx >= R*C) return;
    int r = idx / C, c = idx - r*C;
    dst[(size_t)c*R + r] = __float2bfloat16(src[(size_t)r*ld + off + c]);
}

__global__ void k_pack_wy(float* __restrict__ wy, const float* __restrict__ Wih_d){
    int j = blockIdx.x*256 + threadIdx.x;
    if (j < N4D) wy[j] = Wih_d[(size_t)j*(NTE+1)];
}

// WdTg16[q][e][jj] = bf16(Wih_d[ (jj>>6)*256 + q*64 + (jj&63) ][ 1 + e ])
__global__ void k_pack_wdtg(__hip_bfloat16* __restrict__ dst, const float* __restrict__ Wih_d){
    int idx = blockIdx.x*256 + threadIdx.x;   // total 4*512*256 = 524288
    int q = idx >> 17, rem = idx & 131071;
    int e = rem >> 8, jj = rem & 255;
    int j = ((jj>>6)<<8) + (q<<6) + (jj&63);
    dst[idx] = __float2bfloat16(Wih_d[(size_t)j*(NTE+1) + 1 + e]);
}

// zc[b][j] = b_d[j] + sum_d h0d[b][d] * Whh_d[j][d]
__global__ void k_zc(float* __restrict__ zc, const float* __restrict__ WhhTd,
                     const float* __restrict__ h0d, const float* __restrict__ b_d){
    int b = blockIdx.x, tid = threadIdx.x;
    __shared__ float h0[ND];
    if (tid < ND) h0[tid] = h0d[b*ND + tid];
    __syncthreads();
    for (int j = tid; j < N4D; j += 256){
        float acc = b_d[j];
        #pragma unroll 8
        for (int d=0; d<ND; ++d) acc = fmaf(h0[d], WhhTd[d*N4D + j], acc);
        zc[b*N4D + j] = acc;
    }
}

__global__ void k_dec_init(float* __restrict__ hG, float* __restrict__ yG,
                           unsigned* __restrict__ flags, const float* __restrict__ dec_h0){
    int b = blockIdx.x, tid = threadIdx.x;
    hG[b*ND + tid] = dec_h0[b*ND + tid];
    if (tid < G){ yG[(b<<5) + tid] = 0.f; flags[(b<<5) + tid] = 0u; }
}

// Encoder (r5 structure, proven): 128 blocks = (dir,b), 1024 threads (j2, kh).
__global__ __launch_bounds__(1024) void k_enc(
    const float* __restrict__ x, const float* __restrict__ eh0, const float* __restrict__ ec0,
    const unsigned* __restrict__ whhTf, const unsigned* __restrict__ wihTf, const float* __restrict__ bf,
    const unsigned* __restrict__ whhTb, const unsigned* __restrict__ wihTb, const float* __restrict__ bb,
    unsigned* __restrict__ eo32)
{
    int bid = blockIdx.x;
    int b = bid & 63, dir = bid >> 6;
    int tid = threadIdx.x;
    int j2 = tid & 511, kh = tid >> 9;
    const unsigned* whh = dir ? whhTb : whhTf;   // [d][512 u32]
    const unsigned* wih = dir ? wihTb : wihTf;   // [i][512 u32]
    const float* bias = dir ? bb : bf;

    __shared__ __align__(16) float h_l[NE];
    __shared__ __align__(16) float xt[2][NI];
    __shared__ float zp0[N4E], zp1[N4E];

    float2 bias2 = make_float2(0.f, 0.f);
    if (kh == 0) bias2 = ((const float2*)bias)[j2];

    float cst = 0.f;
    if (tid < NE){
        h_l[tid] = eh0[(dir*NB+b)*NE + tid];
        cst      = ec0[(dir*NB+b)*NE + tid];
    }
    {
        int st0 = dir ? (NS-1) : 0;
        if (tid < 16) ((float4*)xt[0])[tid] = ((const float4*)(x + ((size_t)b*NS+st0)*NI))[tid];
    }
    __syncthreads();

    const unsigned* wihK = wih + (size_t)(kh*32)*512 + j2;
    const unsigned* whhK = whh + (size_t)(kh*128)*512 + j2;
    float* zpme = kh ? zp1 : zp0;

    for (int t=0;t<NS;++t){
        int st = dir ? (NS-1-t) : t;
        float4 xpre = make_float4(0.f,0.f,0.f,0.f);
        if (t+1 < NS && tid < 16){
            int stn = dir ? (NS-2-t) : (t+1);
            xpre = ((const float4*)(x + ((size_t)b*NS+stn)*NI))[tid];
        }
        const float* xc = xt[t&1];
        float x0=bias2.x, y0=bias2.y, x1=0.f, y1=0.f;
        #pragma unroll 8
        for (int ii=0; ii<32; ii+=2){
            int i = kh*32 + ii;
            unsigned wa = wihK[(size_t)ii*512];
            unsigned wb = wihK[(size_t)(ii+1)*512];
            float xa = xc[i], xb = xc[i+1];
            x0 = fmaf(xa, blo(wa), x0); y0 = fmaf(xa, bhi(wa), y0);
            x1 = fmaf(xb, blo(wb), x1); y1 = fmaf(xb, bhi(wb), y1);
        }
        #pragma unroll 8
        for (int dd=0; dd<128; dd+=2){
            int d = kh*128 + dd;
            unsigned wa = whhK[(size_t)dd*512];
            unsigned wb = whhK[(size_t)(dd+1)*512];
            float ha = h_l[d], hb = h_l[d+1];
            x0 = fmaf(ha, blo(wa), x0); y0 = fmaf(ha, bhi(wa), y0);
            x1 = fmaf(hb, blo(wb), x1); y1 = fmaf(hb, bhi(wb), y1);
        }
        ((float2*)zpme)[j2] = make_float2(x0+x1, y0+y1);
        if (t+1 < NS && tid < 16) ((float4*)xt[(t+1)&1])[tid] = xpre;
        __syncthreads();
        if (tid < NE){
            int c = tid;
            float zi = zp0[c]        + zp1[c];
            float zf = zp0[NE+c]     + zp1[NE+c];
            float zg = zp0[2*NE+c]   + zp1[2*NE+c];
            float zo = zp0[3*NE+c]   + zp1[3*NE+c];
            cst = fsig(zf)*cst + fsig(zi)*ftanh(zg);
            float hn = fsig(zo)*ftanh(cst);
            h_l[c] = hn;
            ((unsigned short*)eo32)[((size_t)b*NS+st)*NTE + dir*NE + c] = bfbits(hn);
        }
        __syncthreads();
    }
}

// ep_pk[b][q(4)][dp 128][s 128] (u32 = bf16 pair d=2dp,2dp+1)
__global__ __launch_bounds__(256) void k_encproj(const unsigned* __restrict__ eo32,
        const float* __restrict__ WeT, const float* __restrict__ b_attn,
        unsigned short* __restrict__ ep_pk16){
    int b = blockIdx.y, s0 = blockIdx.x*16, tid = threadIdx.x;
    __shared__ float tile[16*NTE];
    {
        const unsigned* eop = eo32 + (size_t)(b*NS + s0)*256;
        for (int k=0;k<32;++k){
            int wi = k*256 + tid;
            unsigned w = eop[wi];
            int sl = wi>>8, ew = wi&255;
            tile[sl*NTE + 2*ew]   = blo(w);
            tile[sl*NTE + 2*ew+1] = bhi(w);
        }
    }
    __syncthreads();
    float acc[16];
    float ba = b_attn[tid];
    #pragma unroll
    for (int sl=0;sl<16;++sl) acc[sl]=ba;
    #pragma unroll 4
    for (int e4=0;e4<128;++e4){
        float w0 = WeT[(4*e4+0)*ND+tid];
        float w1 = WeT[(4*e4+1)*ND+tid];
        float w2 = WeT[(4*e4+2)*ND+tid];
        float w3 = WeT[(4*e4+3)*ND+tid];
        #pragma unroll
        for (int sl=0;sl<16;++sl){
            const float4 tv = *(const float4*)&tile[sl*NTE + 4*e4];
            acc[sl] = fmaf(tv.x,w0,fmaf(tv.y,w1,fmaf(tv.z,w2,fmaf(tv.w,w3,acc[sl]))));
        }
    }
    #pragma unroll
    for (int sl=0;sl<16;++sl){
        int s = s0+sl;
        size_t wdi = ((size_t)(b*4 + (s>>7))*128 + (tid>>1))*128 + (s&127);
        ep_pk16[wdi*2 + (tid&1)] = bfbits(acc[sl]);
    }
}

// Cooperative decoder: 256 blocks = 64 batches x 4 slices, 1024 threads.
// r5 structure; WhT+WdT streamed from L2; ep quarter in LDS; eo quarter in
// registers. Latency cuts: 64-bit hG loads, yG/out moved into BAR1 shadow,
// tight barrier spin.
__global__ __launch_bounds__(1024) void k_dec(
    const unsigned* __restrict__ eo32,     // [b*s][256] bf16 e-pairs
    const unsigned* __restrict__ ep_pk,    // [b][q][128 dp][128 s] u32
    const unsigned* __restrict__ WhTp,     // [k 256][128] bf16 d-pairs
    const float* __restrict__ v,
    const float* __restrict__ zc, const float* __restrict__ wy,
    const unsigned* __restrict__ WdTp_all, // [q][512 e][128] bf16 jj-pairs
    const float* __restrict__ dec_c0,
    const float* __restrict__ W_lin, const float* __restrict__ b_lin,
    float* __restrict__ hG, float* __restrict__ yG,
    float* __restrict__ ctxG, float* __restrict__ msG,
    unsigned* __restrict__ flags,
    float* __restrict__ out)
{
    int bid = blockIdx.x;
    int b = bid & 63, q = bid >> 6;
    int tid = threadIdx.x;
    int w = tid >> 6, l = tid & 63;

    __shared__ unsigned ep_lds[16384];   // 64 KB: [128 dp][128 s]
    __shared__ float part[2048];         // 8 KB scratch
    __shared__ float h_l[ND];
    __shared__ float2 hv[ND];            // .x = v[d] (persistent), .y = hproj[d]
    __shared__ float scraw[SLICE];
    __shared__ float scores_p[4*33];     // padded [sq][33]
    __shared__ float ctx_l[NTE];
    __shared__ float z_l[256], zc_l[256], wy_l[256];
    __shared__ float c0_l[CELLS], wlh_l[CELLS], wlc_l[SLICE];
    __shared__ float msbuf[8];
    __shared__ float wred[16];
    __shared__ float yprev;

    const unsigned* WdTp = WdTp_all + (size_t)q*NTE*128;

    for (int i=tid; i<16384; i+=1024)
        ep_lds[i] = ep_pk[(size_t)(b*4+q)*16384 + i];
    // eo slice in registers: thread -> (sq = l&3, ep2 = w*16 + (l>>2))
    unsigned eo_reg[32];
    {
        int sq = l & 3, ep2 = w*16 + (l>>2);
        const unsigned* eop = eo32 + (size_t)(b*NS + q*SLICE + sq*32)*256 + ep2;
        #pragma unroll
        for (int ss=0; ss<32; ++ss) eo_reg[ss] = eop[(size_t)ss*256];
    }
    if (tid < 256){
        int jj = tid;
        int j = ((jj>>6)<<8) + (q<<6) + (jj&63);
        zc_l[jj] = zc[b*N4D + j];
        wy_l[jj] = wy[j];
    }
    if (tid < ND) hv[tid] = make_float2(v[tid], 0.f);
    if (tid < CELLS){
        c0_l[tid]  = dec_c0[b*ND + q*CELLS + tid];
        wlh_l[tid] = W_lin[q*CELLS + tid];
    }
    if (tid < SLICE) wlc_l[tid] = W_lin[ND + q*SLICE + tid];
    float blin = b_lin[0];
    __syncthreads();

    for (int t=0; t<NS; ++t){
        // ---- step start: h(t-1) as 64-bit pairs ----
        if (tid < 128){
            unsigned long long hh = ld_ag64((const unsigned long long*)(hG + b*ND) + tid);
            float2 h2 = *(float2*)&hh;
            h_l[2*tid]   = h2.x;
            h_l[2*tid+1] = h2.y;
        }
        __syncthreads();
        // ---- A: hproj = h @ WhT (stream, L2-hot, shared by all blocks) ----
        {
            int d2 = tid & 127, kq = tid >> 7;
            float ax = 0.f, ay = 0.f;
            #pragma unroll 8
            for (int kk=0; kk<32; ++kk){
                int k = kq*32 + kk;
                unsigned ww = WhTp[k*128 + d2];
                float hvv = h_l[k];
                ax = fmaf(hvv, blo(ww), ax); ay = fmaf(hvv, bhi(ww), ay);
            }
            ((float2*)part)[kq*128 + d2] = make_float2(ax, ay);
        }
        __syncthreads();
        if (tid < ND)
            hv[tid].y = part[tid] + part[256+tid] + part[512+tid] + part[768+tid]
                      + part[1024+tid] + part[1280+tid] + part[1536+tid] + part[1792+tid];
        __syncthreads();
        // ---- B: scores from LDS ep (conflict-free) ----
        {
            int sl = tid & 127, dg = tid >> 7;
            float sc = 0.f;
            const unsigned* epl = ep_lds + dg*16*128 + sl;
            #pragma unroll
            for (int k16=0; k16<16; ++k16){
                unsigned ww = epl[k16*128];
                int d = dg*32 + 2*k16;
                float2 a0 = hv[d], a1 = hv[d+1];
                sc += a0.x*ftanh(blo(ww) + a0.y) + a1.x*ftanh(bhi(ww) + a1.y);
            }
            part[dg*128 + sl] = sc;
        }
        __syncthreads();
        if (tid < SLICE){
            float s = 0.f;
            #pragma unroll
            for (int r=0;r<8;++r) s += part[r*128 + tid];
            scraw[tid] = s;
            float wm = wave_max(s);
            if ((tid&63)==0) wred[tid>>6] = wm;
        }
        __syncthreads();
        float smax = fmaxf(wred[0], wred[1]);
        if (tid < SLICE){
            float ev = __expf(scraw[tid] - smax);
            scores_p[(tid>>5)*33 + (tid&31)] = ev;
            float s = wave_sum(ev);
            if ((tid&63)==0) wred[2+(tid>>6)] = s;
        }
        __syncthreads();
        if (tid == 0){
            st_agf(&msG[(b<<5) + 2*q + 0], smax);
            st_agf(&msG[(b<<5) + 2*q + 1], wred[2]+wred[3]);
        }
        // ---- C: context partial; sq folded via shfl ----
        {
            int sq = l & 3, ep2 = w*16 + (l>>2);
            float ax = 0.f, ay = 0.f;
            const float* sp = scores_p + sq*33;
            #pragma unroll
            for (int ss=0; ss<32; ++ss){
                float p = sp[ss];
                unsigned e = eo_reg[ss];
                ax = fmaf(p, blo(e), ax); ay = fmaf(p, bhi(e), ay);
            }
            ax += __shfl_xor(ax, 1, 64); ay += __shfl_xor(ay, 1, 64);
            ax += __shfl_xor(ax, 2, 64); ay += __shfl_xor(ay, 2, 64);
            if (sq == 0) ((float2*)part)[ep2] = make_float2(ax, ay);
        }
        __syncthreads();
        if (tid < 256){
            float2 c2 = ((float2*)part)[tid];
            st_ag64((unsigned long long*)(ctxG + (size_t)(b*4+q)*NTE + 2*tid),
                    *(unsigned long long*)&c2);
        }
        groupbar(flags, b, q, (unsigned)(2*t+1), tid);
        // ---- D: yprev + out (BAR1 shadow) and merge softmax+context ----
        if (tid == 0){
            float y = 0.f;
            if (t > 0){
                y = blin + ld_agf(&yG[(b<<5)+0]) + ld_agf(&yG[(b<<5)+1])
                         + ld_agf(&yG[(b<<5)+2]) + ld_agf(&yG[(b<<5)+3]);
                if (q == 0) out[(size_t)b*NS + (t-1)] = y;
            }
            yprev = y;
        }
        unsigned long long cg[4];
        if (tid < 8) msbuf[tid] = ld_agf(&msG[(b<<5) + tid]);
        if (tid < 256){
            const unsigned long long* cgp =
                (const unsigned long long*)(ctxG + (size_t)b*4*NTE) + tid;
            #pragma unroll
            for (int qq=0; qq<4; ++qq) cg[qq] = ld_ag64(cgp + qq*256);
        }
        __syncthreads();
        if (tid < 256){
            float mm = fmaxf(fmaxf(msbuf[0], msbuf[2]), fmaxf(msbuf[4], msbuf[6]));
            float w0 = __expf(msbuf[0]-mm), w1 = __expf(msbuf[2]-mm),
                  w2 = __expf(msbuf[4]-mm), w3 = __expf(msbuf[6]-mm);
            float inv = __fdividef(1.f, msbuf[1]*w0 + msbuf[3]*w1 + msbuf[5]*w2 + msbuf[7]*w3);
            float2 c0v = *(float2*)&cg[0], c1v = *(float2*)&cg[1];
            float2 c2v = *(float2*)&cg[2], c3v = *(float2*)&cg[3];
            float ax = c0v.x*w0 + c1v.x*w1 + c2v.x*w2 + c3v.x*w3;
            float ay = c0v.y*w0 + c1v.y*w1 + c2v.y*w2 + c3v.y*w3;
            ((float2*)ctx_l)[tid] = make_float2(ax*inv, ay*inv);
        }
        __syncthreads();
        // ---- z j-slice: 8-way e-split over streamed WdT (L2-hot) ----
        {
            int jj2 = tid & 127, eq = tid >> 7;
            float ax = 0.f, ay = 0.f;
            #pragma unroll 8
            for (int ee=0; ee<64; ++ee){
                int e = eq*64 + ee;
                unsigned ww = WdTp[e*128 + jj2];
                float cv = ctx_l[e];
                ax = fmaf(cv, blo(ww), ax); ay = fmaf(cv, bhi(ww), ay);
            }
            ((float2*)part)[eq*128 + jj2] = make_float2(ax, ay);
        }
        __syncthreads();
        if (tid < 256){
            float s = zc_l[tid] + yprev*wy_l[tid];
            #pragma unroll
            for (int r=0; r<8; ++r) s += part[r*256 + tid];
            z_l[tid] = s;
        }
        __syncthreads();
        // ---- gates (64 cells) + y partials ----
        float yp = 0.f;
        if (tid < CELLS){
            float zi=z_l[tid], zf=z_l[64+tid], zg=z_l[128+tid], zo=z_l[192+tid];
            float cn = fsig(zf)*c0_l[tid] + fsig(zi)*ftanh(zg);
            float hn = fsig(zo)*ftanh(cn);
            st_agf(&hG[b*ND + q*CELLS + tid], hn);
            yp = hn * wlh_l[tid];
        } else if (tid < CELLS + SLICE){
            yp = ctx_l[q*SLICE + (tid - CELLS)] * wlc_l[tid - CELLS];
        }
        {
            float s = wave_sum(yp);
            if ((tid&63)==0 && tid < 192) wred[8+(tid>>6)] = s;
        }
        __syncthreads();
        if (tid == 0) st_agf(&yG[(b<<5) + q], wred[8]+wred[9]+wred[10]);
        groupbar(flags, b, q, (unsigned)(2*t+2), tid);
    }
    if (q == 0 && tid == 0){
        out[(size_t)b*NS + (NS-1)] = blin + ld_agf(&yG[(b<<5)+0]) + ld_agf(&yG[(b<<5)+1])
                                          + ld_agf(&yG[(b<<5)+2]) + ld_agf(&yG[(b<<5)+3]);
    }
}

extern "C" void kernel_launch(void* const* d_in, const int* in_sizes, int n_in,
                              void* d_out, int out_size, void* d_ws, size_t ws_size,
                              hipStream_t stream){
    const float* x      = (const float*)d_in[0];
    const float* enc_h0 = (const float*)d_in[1];
    const float* enc_c0 = (const float*)d_in[2];
    const float* dec_h0 = (const float*)d_in[3];
    const float* dec_c0 = (const float*)d_in[4];
    const float* Wih_f  = (const float*)d_in[5];
    const float* Whh_f  = (const float*)d_in[6];
    const float* b_f    = (const float*)d_in[7];
    const float* Wih_b  = (const float*)d_in[8];
    const float* Whh_b  = (const float*)d_in[9];
    const float* b_b    = (const float*)d_in[10];
    const float* W_attn = (const float*)d_in[11];
    const float* b_attn = (const float*)d_in[12];
    const float* v      = (const float*)d_in[13];
    const float* Wih_d  = (const float*)d_in[14];
    const float* Whh_d  = (const float*)d_in[15];
    const float* b_d    = (const float*)d_in[16];
    const float* W_lin  = (const float*)d_in[17];
    const float* b_lin  = (const float*)d_in[18];
    float* out = (float*)d_out;
    char* ws   = (char*)d_ws;

    size_t off = 0;
    auto alloc = [&](size_t bytes)->size_t{ size_t o = off; off += (bytes + 255) & ~(size_t)255; return o; };
    size_t o_eo16   = alloc((size_t)NB*NS*NTE*2);        // bf16 enc_out
    size_t o_eppk   = alloc((size_t)NB*G*128*128*4);     // packed bf16 ep
    size_t o_WihTf  = alloc((size_t)NI*N4E*2);           // [i][1024 j] bf16
    size_t o_WhhTf  = alloc((size_t)NE*N4E*2);           // [d][1024 j] bf16
    size_t o_WihTb  = alloc((size_t)NI*N4E*2);
    size_t o_WhhTb  = alloc((size_t)NE*N4E*2);
    size_t o_WhT16  = alloc((size_t)ND*ND*2);
    size_t o_WeT    = alloc((size_t)NTE*ND*4);
    size_t o_WdTg   = alloc((size_t)G*NTE*256*2);
    size_t o_WhhTd  = alloc((size_t)ND*N4D*4);
    size_t o_zc     = alloc((size_t)NB*N4D*4);
    size_t o_wy     = alloc((size_t)N4D*4);
    size_t o_hG     = alloc((size_t)NB*ND*4);
    size_t o_yG     = alloc((size_t)NB*32*4);
    size_t o_ctxG   = alloc((size_t)NB*G*NTE*4);
    size_t o_msG    = alloc((size_t)NB*32*4);
    size_t o_flags  = alloc((size_t)NB*32*4);
    if (ws_size < off) return;

    auto F   = [&](size_t o)->float*{ return (float*)(ws + o); };
    auto U32 = [&](size_t o)->unsigned*{ return (unsigned*)(ws + o); };
    auto H16 = [&](size_t o)->__hip_bfloat16*{ return (__hip_bfloat16*)(ws + o); };

    auto T32 = [&](size_t dsto, const float* src, int R, int C, int ld, int offc){
        int n = R*C;
        k_transpose<<<dim3((n+255)/256), dim3(256), 0, stream>>>(F(dsto), src, R, C, ld, offc);
    };
    auto T16 = [&](size_t dsto, const float* src, int R, int C, int ld, int offc){
        int n = R*C;
        k_transpose16<<<dim3((n+255)/256), dim3(256), 0, stream>>>(H16(dsto), src, R, C, ld, offc);
    };
    T16(o_WihTf, Wih_f, N4E, NI, NI, 0);
    T16(o_WhhTf, Whh_f, N4E, NE, NE, 0);
    T16(o_WihTb, Wih_b, N4E, NI, NI, 0);
    T16(o_WhhTb, Whh_b, N4E, NE, NE, 0);
    T16(o_WhT16, W_attn, ND, ND, ND+NTE, 0);
    T32(o_WeT,   W_attn, ND, NTE, ND+NTE, ND);
    T32(o_WhhTd, Whh_d, N4D, ND, ND, 0);
    k_pack_wdtg<<<dim3((G*NTE*256)/256), dim3(256), 0, stream>>>(H16(o_WdTg), Wih_d);
    k_pack_wy<<<dim3(4), dim3(256), 0, stream>>>(F(o_wy), Wih_d);
    k_zc<<<dim3(NB), dim3(256), 0, stream>>>(F(o_zc), F(o_WhhTd), dec_h0, b_d);
    k_dec_init<<<dim3(NB), dim3(256), 0, stream>>>(F(o_hG), F(o_yG), (unsigned*)(ws+o_flags), dec_h0);

    k_enc<<<dim3(2*NB), dim3(1024), 0, stream>>>(x, enc_h0, enc_c0,
        U32(o_WhhTf), U32(o_WihTf), b_f, U32(o_WhhTb), U32(o_WihTb), b_b, U32(o_eo16));

    k_encproj<<<dim3(NS/16, NB), dim3(256), 0, stream>>>(U32(o_eo16), F(o_WeT), b_attn,
        (unsigned short*)(ws+o_eppk));

    k_dec<<<dim3(NB*G), dim3(1024), 0, stream>>>(U32(o_eo16), U32(o_eppk),
        U32(o_WhT16), v, F(o_zc), F(o_wy), U32(o_WdTg), dec_c0, W_lin, b_lin,
        F(o_hG), F(o_yG), F(o_ctxG), F(o_msG), (unsigned*)(ws+o_flags), out);
}

// Round 12
// 18032.837 us; speedup vs baseline: 3.1740x; 1.0203x over previous
//
#include <hip/hip_runtime.h>
#include <hip/hip_bf16.h>

#define NB 64
#define NS 512
#define NI 64
#define NE 256
#define ND 256
#define N4E 1024
#define N4D 1024
#define NTE 512   // 2*E
#define G 4
#define SLICE 128 // NS/G

__device__ __forceinline__ float fsig(float x){
    return __fdividef(1.f, 1.f + __expf(-x));
}
__device__ __forceinline__ float ftanh(float x){
    return 1.f - __fdividef(2.f, 1.f + __expf(2.f*x));
}
__device__ __forceinline__ float wave_sum(float v){
    #pragma unroll
    for (int o=32;o>0;o>>=1) v += __shfl_xor(v, o, 64);
    return v;
}
__device__ __forceinline__ float wave_max(float v){
    #pragma unroll
    for (int o=32;o>0;o>>=1) v = fmaxf(v, __shfl_xor(v, o, 64));
    return v;
}
__device__ __forceinline__ float blo(unsigned u){ return __uint_as_float(u<<16); }
__device__ __forceinline__ float bhi(unsigned u){ return __uint_as_float(u & 0xffff0000u); }
__device__ __forceinline__ unsigned short bfbits(float f){
    __hip_bfloat16 h = __float2bfloat16(f);
    return *(unsigned short*)&h;
}
__device__ __forceinline__ float ld_agf(const float* p){
    return __hip_atomic_load(p, __ATOMIC_RELAXED, __HIP_MEMORY_SCOPE_AGENT);
}
__device__ __forceinline__ void st_agf(float* p, float v){
    __hip_atomic_store(p, v, __ATOMIC_RELAXED, __HIP_MEMORY_SCOPE_AGENT);
}
__device__ __forceinline__ unsigned long long ld_ag64(const unsigned long long* p){
    return __hip_atomic_load(p, __ATOMIC_RELAXED, __HIP_MEMORY_SCOPE_AGENT);
}
__device__ __forceinline__ void st_ag64(unsigned long long* p, unsigned long long v){
    __hip_atomic_store(p, v, __ATOMIC_RELAXED, __HIP_MEMORY_SCOPE_AGENT);
}

// group barrier: per-q flag words (padded 128B per batch); tight 4-lane poll.
__device__ __forceinline__ void groupbar(unsigned* flags, int b, int q,
                                         unsigned tgt, int tid){
    __syncthreads();
    if (tid == 0)
        __hip_atomic_store(&flags[(b<<5)+q], tgt, __ATOMIC_RELAXED, __HIP_MEMORY_SCOPE_AGENT);
    if (tid < G){
        while (__hip_atomic_load(&flags[(b<<5)+tid], __ATOMIC_RELAXED,
                                 __HIP_MEMORY_SCOPE_AGENT) < tgt)
            ;
    }
    __syncthreads();
}

// fp32 transpose: dst[c*R + r] = src[r*ld + off + c]
__global__ void k_transpose(float* __restrict__ dst, const float* __restrict__ src,
                            int R, int C, int ld, int off){
    int idx = blockIdx.x*256 + threadIdx.x;
    if (idx >= R*C) return;
    int r = idx / C, c = idx - r*C;
    dst[(size_t)c*R + r] = src[(size_t)r*ld + off + c];
}
// bf16 transpose
__global__ void k_transpose16(__hip_bfloat16* __restrict__ dst, const float* __restrict__ src,
                              int R, int C, int ld, int off){
    int idx = blockIdx.x*256 + threadIdx.x;
    if (idx >= R*C) return;
    int r = idx / C, c = idx - r*C;
    dst[(size_t)c*R + r] = __float2bfloat16(src[(size_t)r*ld + off + c]);
}

__global__ void k_pack_wy(float* __restrict__ wy, const float* __restrict__ Wih_d){
    int j = blockIdx.x*256 + threadIdx.x;
    if (j < N4D) wy[j] = Wih_d[(size_t)j*(NTE+1)];
}

// Full WdT, j-pair-major rows: dst[e*512 + j2] = pack(Wih_d[2j2][1+e], Wih_d[2j2+1][1+e])
__global__ void k_pack_wdtf(unsigned* __restrict__ dst, const float* __restrict__ Wih_d){
    int idx = blockIdx.x*256 + threadIdx.x;   // total 512*512 = 262144
    int e = idx >> 9, j2 = idx & 511;
    unsigned lo = bfbits(Wih_d[(size_t)(2*j2)*(NTE+1) + 1 + e]);
    unsigned hi = bfbits(Wih_d[(size_t)(2*j2+1)*(NTE+1) + 1 + e]);
    dst[idx] = lo | (hi<<16);
}

// zc[b][j] = b_d[j] + sum_d h0d[b][d] * Whh_d[j][d]
__global__ void k_zc(float* __restrict__ zc, const float* __restrict__ WhhTd,
                     const float* __restrict__ h0d, const float* __restrict__ b_d){
    int b = blockIdx.x, tid = threadIdx.x;
    __shared__ float h0[ND];
    if (tid < ND) h0[tid] = h0d[b*ND + tid];
    __syncthreads();
    for (int j = tid; j < N4D; j += 256){
        float acc = b_d[j];
        #pragma unroll 8
        for (int d=0; d<ND; ++d) acc = fmaf(h0[d], WhhTd[d*N4D + j], acc);
        zc[b*N4D + j] = acc;
    }
}

__global__ void k_dec_init(unsigned* __restrict__ flags){
    int b = blockIdx.x, tid = threadIdx.x;
    if (tid < G) flags[(b<<5) + tid] = 0u;
}

// Encoder (r5 structure, proven): 128 blocks = (dir,b), 1024 threads (j2, kh).
__global__ __launch_bounds__(1024) void k_enc(
    const float* __restrict__ x, const float* __restrict__ eh0, const float* __restrict__ ec0,
    const unsigned* __restrict__ whhTf, const unsigned* __restrict__ wihTf, const float* __restrict__ bf,
    const unsigned* __restrict__ whhTb, const unsigned* __restrict__ wihTb, const float* __restrict__ bb,
    unsigned* __restrict__ eo32)
{
    int bid = blockIdx.x;
    int b = bid & 63, dir = bid >> 6;
    int tid = threadIdx.x;
    int j2 = tid & 511, kh = tid >> 9;
    const unsigned* whh = dir ? whhTb : whhTf;   // [d][512 u32]
    const unsigned* wih = dir ? wihTb : wihTf;   // [i][512 u32]
    const float* bias = dir ? bb : bf;

    __shared__ __align__(16) float h_l[NE];
    __shared__ __align__(16) float xt[2][NI];
    __shared__ float zp0[N4E], zp1[N4E];

    float2 bias2 = make_float2(0.f, 0.f);
    if (kh == 0) bias2 = ((const float2*)bias)[j2];

    float cst = 0.f;
    if (tid < NE){
        h_l[tid] = eh0[(dir*NB+b)*NE + tid];
        cst      = ec0[(dir*NB+b)*NE + tid];
    }
    {
        int st0 = dir ? (NS-1) : 0;
        if (tid < 16) ((float4*)xt[0])[tid] = ((const float4*)(x + ((size_t)b*NS+st0)*NI))[tid];
    }
    __syncthreads();

    const unsigned* wihK = wih + (size_t)(kh*32)*512 + j2;
    const unsigned* whhK = whh + (size_t)(kh*128)*512 + j2;
    float* zpme = kh ? zp1 : zp0;

    for (int t=0;t<NS;++t){
        int st = dir ? (NS-1-t) : t;
        float4 xpre = make_float4(0.f,0.f,0.f,0.f);
        if (t+1 < NS && tid < 16){
            int stn = dir ? (NS-2-t) : (t+1);
            xpre = ((const float4*)(x + ((size_t)b*NS+stn)*NI))[tid];
        }
        const float* xc = xt[t&1];
        float x0=bias2.x, y0=bias2.y, x1=0.f, y1=0.f;
        #pragma unroll 8
        for (int ii=0; ii<32; ii+=2){
            int i = kh*32 + ii;
            unsigned wa = wihK[(size_t)ii*512];
            unsigned wb = wihK[(size_t)(ii+1)*512];
            float xa = xc[i], xb = xc[i+1];
            x0 = fmaf(xa, blo(wa), x0); y0 = fmaf(xa, bhi(wa), y0);
            x1 = fmaf(xb, blo(wb), x1); y1 = fmaf(xb, bhi(wb), y1);
        }
        #pragma unroll 8
        for (int dd=0; dd<128; dd+=2){
            int d = kh*128 + dd;
            unsigned wa = whhK[(size_t)dd*512];
            unsigned wb = whhK[(size_t)(dd+1)*512];
            float ha = h_l[d], hb = h_l[d+1];
            x0 = fmaf(ha, blo(wa), x0); y0 = fmaf(ha, bhi(wa), y0);
            x1 = fmaf(hb, blo(wb), x1); y1 = fmaf(hb, bhi(wb), y1);
        }
        ((float2*)zpme)[j2] = make_float2(x0+x1, y0+y1);
        if (t+1 < NS && tid < 16) ((float4*)xt[(t+1)&1])[tid] = xpre;
        __syncthreads();
        if (tid < NE){
            int c = tid;
            float zi = zp0[c]        + zp1[c];
            float zf = zp0[NE+c]     + zp1[NE+c];
            float zg = zp0[2*NE+c]   + zp1[2*NE+c];
            float zo = zp0[3*NE+c]   + zp1[3*NE+c];
            cst = fsig(zf)*cst + fsig(zi)*ftanh(zg);
            float hn = fsig(zo)*ftanh(cst);
            h_l[c] = hn;
            ((unsigned short*)eo32)[((size_t)b*NS+st)*NTE + dir*NE + c] = bfbits(hn);
        }
        __syncthreads();
    }
}

// ep_pk[b][q(4)][dp 128][s 128] (u32 = bf16 pair d=2dp,2dp+1)
__global__ __launch_bounds__(256) void k_encproj(const unsigned* __restrict__ eo32,
        const float* __restrict__ WeT, const float* __restrict__ b_attn,
        unsigned short* __restrict__ ep_pk16){
    int b = blockIdx.y, s0 = blockIdx.x*16, tid = threadIdx.x;
    __shared__ float tile[16*NTE];
    {
        const unsigned* eop = eo32 + (size_t)(b*NS + s0)*256;
        for (int k=0;k<32;++k){
            int wi = k*256 + tid;
            unsigned w = eop[wi];
            int sl = wi>>8, ew = wi&255;
            tile[sl*NTE + 2*ew]   = blo(w);
            tile[sl*NTE + 2*ew+1] = bhi(w);
        }
    }
    __syncthreads();
    float acc[16];
    float ba = b_attn[tid];
    #pragma unroll
    for (int sl=0;sl<16;++sl) acc[sl]=ba;
    #pragma unroll 4
    for (int e4=0;e4<128;++e4){
        float w0 = WeT[(4*e4+0)*ND+tid];
        float w1 = WeT[(4*e4+1)*ND+tid];
        float w2 = WeT[(4*e4+2)*ND+tid];
        float w3 = WeT[(4*e4+3)*ND+tid];
        #pragma unroll
        for (int sl=0;sl<16;++sl){
            const float4 tv = *(const float4*)&tile[sl*NTE + 4*e4];
            acc[sl] = fmaf(tv.x,w0,fmaf(tv.y,w1,fmaf(tv.z,w2,fmaf(tv.w,w3,acc[sl]))));
        }
    }
    #pragma unroll
    for (int sl=0;sl<16;++sl){
        int s = s0+sl;
        size_t wdi = ((size_t)(b*4 + (s>>7))*128 + (tid>>1))*128 + (s&127);
        ep_pk16[wdi*2 + (tid&1)] = bfbits(acc[sl]);
    }
}

// Cooperative decoder: 256 blocks = 64 batches x 4 slices, 1024 threads.
// ONE barrier per step: scores/ctx are q-sliced (ep LDS quarter, eo regs),
// everything after the ctx merge (z, gates, y) is computed redundantly &
// bit-identically in every block -> no h/y exchange, no second barrier.
__global__ __launch_bounds__(1024) void k_dec(
    const unsigned* __restrict__ eo32,     // [b*s][256] bf16 e-pairs
    const unsigned* __restrict__ ep_pk,    // [b][q][128 dp][128 s] u32
    const unsigned* __restrict__ WhTp,     // [k 256][128] bf16 d-pairs
    const float* __restrict__ v,
    const float* __restrict__ zc, const float* __restrict__ wy,
    const uint2* __restrict__ wdT2,        // [512 e][256] uint2 (4 adjacent j)
    const float* __restrict__ dec_h0, const float* __restrict__ dec_c0,
    const float* __restrict__ W_lin, const float* __restrict__ b_lin,
    float* __restrict__ ctxG, float* __restrict__ msG,
    unsigned* __restrict__ flags,
    float* __restrict__ out)
{
    int bid = blockIdx.x;
    int b = bid & 63, q = bid >> 6;
    int tid = threadIdx.x;
    int w = tid >> 6, l = tid & 63;

    __shared__ unsigned ep_lds[16384];   // 64 KB: [128 dp][128 s]
    __shared__ float part[4096];         // 16 KB scratch
    __shared__ float h_l[ND];
    __shared__ float2 hv[ND];            // .x = v[d] (persistent), .y = hproj[d]
    __shared__ float scraw[SLICE];
    __shared__ float scores_p[4*33];     // padded [sq][33]
    __shared__ float ctx_l[NTE];
    __shared__ float z_l[N4D], zc_l[N4D], wy_l[N4D];
    __shared__ float c0_l[ND], wlh_l[ND], wlc_l[NTE];
    __shared__ float msbuf[8];
    __shared__ float wred[16];
    __shared__ float yprev;

    for (int i=tid; i<16384; i+=1024)
        ep_lds[i] = ep_pk[(size_t)(b*4+q)*16384 + i];
    // eo slice in registers: thread -> (sq = l&3, ep2 = w*16 + (l>>2))
    unsigned eo_reg[32];
    {
        int sq = l & 3, ep2 = w*16 + (l>>2);
        const unsigned* eop = eo32 + (size_t)(b*NS + q*SLICE + sq*32)*256 + ep2;
        #pragma unroll
        for (int ss=0; ss<32; ++ss) eo_reg[ss] = eop[(size_t)ss*256];
    }
    zc_l[tid] = zc[b*N4D + tid];
    wy_l[tid] = wy[tid];
    if (tid < ND){
        hv[tid]    = make_float2(v[tid], 0.f);
        h_l[tid]   = dec_h0[b*ND + tid];
        c0_l[tid]  = dec_c0[b*ND + tid];
        wlh_l[tid] = W_lin[tid];
    }
    if (tid < NTE) wlc_l[tid] = W_lin[ND + tid];
    if (tid == 0) yprev = 0.f;
    float blin = b_lin[0];
    __syncthreads();

    for (int t=0; t<NS; ++t){
        // ---- A: hproj = h @ WhT (stream, L2-hot, shared by all blocks) ----
        {
            int d2 = tid & 127, kq = tid >> 7;
            float ax = 0.f, ay = 0.f;
            #pragma unroll 8
            for (int kk=0; kk<32; ++kk){
                int k = kq*32 + kk;
                unsigned ww = WhTp[k*128 + d2];
                float hvv = h_l[k];
                ax = fmaf(hvv, blo(ww), ax); ay = fmaf(hvv, bhi(ww), ay);
            }
            ((float2*)part)[kq*128 + d2] = make_float2(ax, ay);
        }
        __syncthreads();
        if (tid < ND)
            hv[tid].y = part[tid] + part[256+tid] + part[512+tid] + part[768+tid]
                      + part[1024+tid] + part[1280+tid] + part[1536+tid] + part[1792+tid];
        __syncthreads();
        // ---- B: scores from LDS ep (conflict-free) ----
        {
            int sl = tid & 127, dg = tid >> 7;
            float sc = 0.f;
            const unsigned* epl = ep_lds + dg*16*128 + sl;
            #pragma unroll
            for (int k16=0; k16<16; ++k16){
                unsigned ww = epl[k16*128];
                int d = dg*32 + 2*k16;
                float2 a0 = hv[d], a1 = hv[d+1];
                sc += a0.x*ftanh(blo(ww) + a0.y) + a1.x*ftanh(bhi(ww) + a1.y);
            }
            part[dg*128 + sl] = sc;
        }
        __syncthreads();
        if (tid < SLICE){
            float s = 0.f;
            #pragma unroll
            for (int r=0;r<8;++r) s += part[r*128 + tid];
            scraw[tid] = s;
            float wm = wave_max(s);
            if ((tid&63)==0) wred[tid>>6] = wm;
        }
        __syncthreads();
        float smax = fmaxf(wred[0], wred[1]);
        if (tid < SLICE){
            float ev = __expf(scraw[tid] - smax);
            scores_p[(tid>>5)*33 + (tid&31)] = ev;
            float s = wave_sum(ev);
            if ((tid&63)==0) wred[2+(tid>>6)] = s;
        }
        __syncthreads();
        if (tid == 0){
            st_agf(&msG[(b<<5) + 2*q + 0], smax);
            st_agf(&msG[(b<<5) + 2*q + 1], wred[2]+wred[3]);
        }
        // ---- C: context partial; sq folded via shfl ----
        {
            int sq = l & 3, ep2 = w*16 + (l>>2);
            float ax = 0.f, ay = 0.f;
            const float* sp = scores_p + sq*33;
            #pragma unroll
            for (int ss=0; ss<32; ++ss){
                float p = sp[ss];
                unsigned e = eo_reg[ss];
                ax = fmaf(p, blo(e), ax); ay = fmaf(p, bhi(e), ay);
            }
            ax += __shfl_xor(ax, 1, 64); ay += __shfl_xor(ay, 1, 64);
            ax += __shfl_xor(ax, 2, 64); ay += __shfl_xor(ay, 2, 64);
            if (sq == 0) ((float2*)part)[ep2] = make_float2(ax, ay);
        }
        __syncthreads();
        if (tid < 256){
            float2 c2 = ((float2*)part)[tid];
            st_ag64((unsigned long long*)(ctxG + (size_t)(b*4+q)*NTE + 2*tid),
                    *(unsigned long long*)&c2);
        }
        groupbar(flags, b, q, (unsigned)(t+1), tid);
        // ---- D: merge softmax+context (full ctx in every block) ----
        unsigned long long cg[4];
        if (tid < 8) msbuf[tid] = ld_agf(&msG[(b<<5) + tid]);
        if (tid < 256){
            const unsigned long long* cgp =
                (const unsigned long long*)(ctxG + (size_t)b*4*NTE) + tid;
            #pragma unroll
            for (int qq=0; qq<4; ++qq) cg[qq] = ld_ag64(cgp + qq*256);
        }
        __syncthreads();
        if (tid < 256){
            float mm = fmaxf(fmaxf(msbuf[0], msbuf[2]), fmaxf(msbuf[4], msbuf[6]));
            float w0 = __expf(msbuf[0]-mm), w1 = __expf(msbuf[2]-mm),
                  w2 = __expf(msbuf[4]-mm), w3 = __expf(msbuf[6]-mm);
            float inv = __fdividef(1.f, msbuf[1]*w0 + msbuf[3]*w1 + msbuf[5]*w2 + msbuf[7]*w3);
            float2 c0v = *(float2*)&cg[0], c1v = *(float2*)&cg[1];
            float2 c2v = *(float2*)&cg[2], c3v = *(float2*)&cg[3];
            float ax = c0v.x*w0 + c1v.x*w1 + c2v.x*w2 + c3v.x*w3;
            float ay = c0v.y*w0 + c1v.y*w1 + c2v.y*w2 + c3v.y*w3;
            ((float2*)ctx_l)[tid] = make_float2(ax*inv, ay*inv);
        }
        __syncthreads();
        // ---- E: FULL z = zc + y*wy + ctx @ WdT (1 MB stream, L2-shared) ----
        {
            int p4 = tid & 255, eq = tid >> 8;        // 4 e-groups x 128 e
            float a0=0.f, a1=0.f, a2=0.f, a3=0.f;
            const uint2* wp = wdT2 + (size_t)(eq*128)*256 + p4;
            #pragma unroll 8
            for (int ee=0; ee<128; ++ee){
                uint2 ww = wp[(size_t)ee*256];
                float cv = ctx_l[eq*128 + ee];
                a0 = fmaf(cv, blo(ww.x), a0); a1 = fmaf(cv, bhi(ww.x), a1);
                a2 = fmaf(cv, blo(ww.y), a2); a3 = fmaf(cv, bhi(ww.y), a3);
            }
            ((float4*)part)[eq*256 + p4] = make_float4(a0,a1,a2,a3);
        }
        __syncthreads();
        z_l[tid] = zc_l[tid] + yprev*wy_l[tid]
                 + part[tid] + part[1024+tid] + part[2048+tid] + part[3072+tid];
        __syncthreads();
        // ---- F: full gates (256 cells, redundant across q) + full y ----
        float yp = 0.f;
        if (tid < ND){
            float zi=z_l[tid], zf=z_l[ND+tid], zg=z_l[2*ND+tid], zo=z_l[3*ND+tid];
            float cn = fsig(zf)*c0_l[tid] + fsig(zi)*ftanh(zg);
            float hn = fsig(zo)*ftanh(cn);
            h_l[tid] = hn;
            yp = hn * wlh_l[tid];
        } else if (tid < ND + NTE){
            yp = ctx_l[tid - ND] * wlc_l[tid - ND];
        }
        {
            float s = wave_sum(yp);
            if ((tid&63)==0 && tid < 768) wred[tid>>6] = s;
        }
        __syncthreads();
        if (tid == 0){
            float y = blin;
            #pragma unroll
            for (int g=0; g<12; ++g) y += wred[g];
            if (q == 0) out[(size_t)b*NS + t] = y;
            yprev = y;
        }
        __syncthreads();
    }
}

extern "C" void kernel_launch(void* const* d_in, const int* in_sizes, int n_in,
                              void* d_out, int out_size, void* d_ws, size_t ws_size,
                              hipStream_t stream){
    const float* x      = (const float*)d_in[0];
    const float* enc_h0 = (const float*)d_in[1];
    const float* enc_c0 = (const float*)d_in[2];
    const float* dec_h0 = (const float*)d_in[3];
    const float* dec_c0 = (const float*)d_in[4];
    const float* Wih_f  = (const float*)d_in[5];
    const float* Whh_f  = (const float*)d_in[6];
    const float* b_f    = (const float*)d_in[7];
    const float* Wih_b  = (const float*)d_in[8];
    const float* Whh_b  = (const float*)d_in[9];
    const float* b_b    = (const float*)d_in[10];
    const float* W_attn = (const float*)d_in[11];
    const float* b_attn = (const float*)d_in[12];
    const float* v      = (const float*)d_in[13];
    const float* Wih_d  = (const float*)d_in[14];
    const float* Whh_d  = (const float*)d_in[15];
    const float* b_d    = (const float*)d_in[16];
    const float* W_lin  = (const float*)d_in[17];
    const float* b_lin  = (const float*)d_in[18];
    float* out = (float*)d_out;
    char* ws   = (char*)d_ws;

    size_t off = 0;
    auto alloc = [&](size_t bytes)->size_t{ size_t o = off; off += (bytes + 255) & ~(size_t)255; return o; };
    size_t o_eo16   = alloc((size_t)NB*NS*NTE*2);        // bf16 enc_out
    size_t o_eppk   = alloc((size_t)NB*G*128*128*4);     // packed bf16 ep
    size_t o_WihTf  = alloc((size_t)NI*N4E*2);           // [i][1024 j] bf16
    size_t o_WhhTf  = alloc((size_t)NE*N4E*2);           // [d][1024 j] bf16
    size_t o_WihTb  = alloc((size_t)NI*N4E*2);
    size_t o_WhhTb  = alloc((size_t)NE*N4E*2);
    size_t o_WhT16  = alloc((size_t)ND*ND*2);
    size_t o_WeT    = alloc((size_t)NTE*ND*4);
    size_t o_Wdtf   = alloc((size_t)NTE*512*4);          // full WdT u32 [e][512]
    size_t o_WhhTd  = alloc((size_t)ND*N4D*4);
    size_t o_zc     = alloc((size_t)NB*N4D*4);
    size_t o_wy     = alloc((size_t)N4D*4);
    size_t o_ctxG   = alloc((size_t)NB*G*NTE*4);
    size_t o_msG    = alloc((size_t)NB*32*4);
    size_t o_flags  = alloc((size_t)NB*32*4);
    if (ws_size < off) return;

    auto F   = [&](size_t o)->float*{ return (float*)(ws + o); };
    auto U32 = [&](size_t o)->unsigned*{ return (unsigned*)(ws + o); };
    auto H16 = [&](size_t o)->__hip_bfloat16*{ return (__hip_bfloat16*)(ws + o); };

    auto T32 = [&](size_t dsto, const float* src, int R, int C, int ld, int offc){
        int n = R*C;
        k_transpose<<<dim3((n+255)/256), dim3(256), 0, stream>>>(F(dsto), src, R, C, ld, offc);
    };
    auto T16 = [&](size_t dsto, const float* src, int R, int C, int ld, int offc){
        int n = R*C;
        k_transpose16<<<dim3((n+255)/256), dim3(256), 0, stream>>>(H16(dsto), src, R, C, ld, offc);
    };
    T16(o_WihTf, Wih_f, N4E, NI, NI, 0);
    T16(o_WhhTf, Whh_f, N4E, NE, NE, 0);
    T16(o_WihTb, Wih_b, N4E, NI, NI, 0);
    T16(o_WhhTb, Whh_b, N4E, NE, NE, 0);
    T16(o_WhT16, W_attn, ND, ND, ND+NTE, 0);
    T32(o_WeT,   W_attn, ND, NTE, ND+NTE, ND);
    T32(o_WhhTd, Whh_d, N4D, ND, ND, 0);
    k_pack_wdtf<<<dim3((NTE*512)/256), dim3(256), 0, stream>>>(U32(o_Wdtf), Wih_d);
    k_pack_wy<<<dim3(4), dim3(256), 0, stream>>>(F(o_wy), Wih_d);
    k_zc<<<dim3(NB), dim3(256), 0, stream>>>(F(o_zc), F(o_WhhTd), dec_h0, b_d);
    k_dec_init<<<dim3(NB), dim3(64), 0, stream>>>((unsigned*)(ws+o_flags));

    k_enc<<<dim3(2*NB), dim3(1024), 0, stream>>>(x, enc_h0, enc_c0,
        U32(o_WhhTf), U32(o_WihTf), b_f, U32(o_WhhTb), U32(o_WihTb), b_b, U32(o_eo16));

    k_encproj<<<dim3(NS/16, NB), dim3(256), 0, stream>>>(U32(o_eo16), F(o_WeT), b_attn,
        (unsigned short*)(ws+o_eppk));

    k_dec<<<dim3(NB*G), dim3(1024), 0, stream>>>(U32(o_eo16), U32(o_eppk),
        U32(o_WhT16), v, F(o_zc), F(o_wy), (const uint2*)(ws+o_Wdtf),
        dec_h0, dec_c0, W_lin, b_lin,
        F(o_ctxG), F(o_msG), (unsigned*)(ws+o_flags), out);
}